// Round 2
// baseline (12721.028 us; speedup 1.0000x reference)
//
#include <hip/hip_runtime.h>
#include <math.h>

// Problem constants (QwenMoeTransformerDecoder: B=2,S=2048,H=2048,E=8,K=4)
static constexpr int BB   = 2;
static constexpr int SS   = 2048;
static constexpr int HH   = 2048;
static constexpr int TT   = BB * SS;   // 4096 tokens
static constexpr int EE   = 8;
static constexpr int KSEL = 4;
static constexpr int IMOE = 1408;
static constexpr int ISH  = 5632;      // = 4 * IMOE (chunked)
static constexpr int NQ   = 16;
static constexpr int NKV  = 2;
static constexpr int DH   = 128;

// ---------------------------------------------------------------- RMSNorm
__global__ __launch_bounds__(256)
void rmsnorm_k(const float* __restrict__ x, const float* __restrict__ sc,
               float* __restrict__ o)
{
    const int row = blockIdx.x;
    const float4* xr = (const float4*)(x + (size_t)row * HH);
    const float4* sr = (const float4*)sc;
    float4* orow = (float4*)(o + (size_t)row * HH);
    float ss = 0.f;
    for (int i = threadIdx.x; i < HH / 4; i += 256) {
        float4 v = xr[i];
        ss += v.x * v.x + v.y * v.y + v.z * v.z + v.w * v.w;
    }
#pragma unroll
    for (int off = 32; off > 0; off >>= 1) ss += __shfl_down(ss, off, 64);
    __shared__ float red[4];
    if ((threadIdx.x & 63) == 0) red[threadIdx.x >> 6] = ss;
    __syncthreads();
    const float tot = red[0] + red[1] + red[2] + red[3];
    const float inv = rsqrtf(tot / (float)HH + 1e-5f);
    for (int i = threadIdx.x; i < HH / 4; i += 256) {
        float4 v = xr[i]; float4 s = sr[i];
        float4 w;
        w.x = v.x * inv * s.x; w.y = v.y * inv * s.y;
        w.z = v.z * inv * s.z; w.w = v.w * inv * s.w;
        orow[i] = w;
    }
}

// ---------------------------------------------------------------- zero fill (float4 granularity)
__global__ __launch_bounds__(256)
void zero_k(float* __restrict__ p, int n4)
{
    const int i = blockIdx.x * 256 + threadIdx.x;
    if (i < n4) ((float4*)p)[i] = make_float4(0.f, 0.f, 0.f, 0.f);
}

// ---------------------------------------------------------------- generic f32 GEMM
// C[m,n] = dot(A[arow?arow[m]:m,:],B[:,n]) (+bias[n]) , *rowscale[m], (+=C), (+add1), (+add2)
// Optional crow[] indirection on the C row (crow[m]<0 -> row skipped).
// Optional mlim (device ptr): blocks with m0 >= *mlim exit (sparse-expert tail).
// 128x128 tile, BK=16, 256 threads, 8x8 microtile (2x2 blocks of 4x4 at
// row/col offsets {tr*4, 64+tr*4} x {tc*4, 64+tc*4} -> LDS reads are
// broadcast (A) or 2-way (B) = conflict-free).  Next K-tile is prefetched
// into registers right after the barrier so the global load overlaps the
// 16-deep FMA loop.  K accumulation order identical to the 64x64 version.
__global__ __launch_bounds__(256)
void gemm_k(const float* __restrict__ A, int lda,
            const float* __restrict__ Bm, int ldb,
            float* __restrict__ C, int ldc, int K,
            const float* __restrict__ bias,
            const float* __restrict__ rowscale,
            const float* __restrict__ add1,
            const float* __restrict__ add2,
            int accumulate,
            const int* __restrict__ arow,
            const int* __restrict__ crow,
            const int* __restrict__ mlim)
{
    const int m0 = blockIdx.y * 128;
    if (mlim && m0 >= *mlim) return;       // uniform exit, before any barrier

    __shared__ float As[16][132];   // As[k][m] (transposed store; stride 132)
    __shared__ float Bs[16][132];   // Bs[k][n]
    const int t  = threadIdx.x;
    const int n0 = blockIdx.x * 128;
    const int tr = t >> 4;          // 0..15 -> rows {4tr..4tr+3, 64+4tr..}
    const int tc = t & 15;          // 0..15 -> cols {4tc..4tc+3, 64+4tc..}
    const int ar = t >> 1;          // 0..127 A-row in tile
    const int ac = (t & 1) << 3;    // 0 or 8: k-offset (8 floats per thread)
    const int br = t >> 4;          // 0..15 B k-row
    const int bc = (t & 15) << 3;   // 0..120 n-offset (8 floats per thread)

    int arow_eff = m0 + ar;
    if (arow) { const int r = arow[arow_eff]; arow_eff = (r < 0) ? 0 : r; }
    const float* Ap = A + (size_t)arow_eff * lda + ac;
    const float* Bp = Bm + (size_t)br * ldb + n0 + bc;

    float4 a0 = *(const float4*)(Ap);
    float4 a1 = *(const float4*)(Ap + 4);
    float4 b0 = *(const float4*)(Bp);
    float4 b1 = *(const float4*)(Bp + 4);

    float acc[8][8] = {};
    for (int k0 = 0; k0 < K; k0 += 16) {
        __syncthreads();                       // prior compute done with LDS
        As[ac + 0][ar] = a0.x; As[ac + 1][ar] = a0.y;
        As[ac + 2][ar] = a0.z; As[ac + 3][ar] = a0.w;
        As[ac + 4][ar] = a1.x; As[ac + 5][ar] = a1.y;
        As[ac + 6][ar] = a1.z; As[ac + 7][ar] = a1.w;
        *(float4*)&Bs[br][bc]     = b0;
        *(float4*)&Bs[br][bc + 4] = b1;
        __syncthreads();                       // tile ready
        if (k0 + 16 < K) {                     // prefetch next K-tile (overlaps FMAs)
            a0 = *(const float4*)(Ap + k0 + 16);
            a1 = *(const float4*)(Ap + k0 + 20);
            b0 = *(const float4*)(Bp + (size_t)(k0 + 16) * ldb);
            b1 = *(const float4*)(Bp + (size_t)(k0 + 16) * ldb + 4);
        }
#pragma unroll
        for (int kk = 0; kk < 16; ++kk) {
            const float4 aA = *(const float4*)&As[kk][tr << 2];
            const float4 aB = *(const float4*)&As[kk][64 + (tr << 2)];
            const float4 bA = *(const float4*)&Bs[kk][tc << 2];
            const float4 bB = *(const float4*)&Bs[kk][64 + (tc << 2)];
            const float aa[8] = {aA.x, aA.y, aA.z, aA.w, aB.x, aB.y, aB.z, aB.w};
            const float bb[8] = {bA.x, bA.y, bA.z, bA.w, bB.x, bB.y, bB.z, bB.w};
#pragma unroll
            for (int i = 0; i < 8; ++i)
#pragma unroll
                for (int j = 0; j < 8; ++j)
                    acc[i][j] += aa[i] * bb[j];
        }
    }
#pragma unroll
    for (int i = 0; i < 8; ++i) {
        const int mrow = (i < 4) ? ((tr << 2) + i) : (64 + (tr << 2) + i - 4);
        const int m = m0 + mrow;
        int cm = m;
        if (crow) { cm = crow[m]; if (cm < 0) continue; }
        const float rs = rowscale ? rowscale[m] : 1.f;
#pragma unroll
        for (int jg = 0; jg < 2; ++jg) {
#pragma unroll
            for (int j = 0; j < 4; ++j) {
                const int n = n0 + (jg << 6) + (tc << 2) + j;
                float v = acc[i][(jg << 2) + j];
                if (bias) v += bias[n];
                v *= rs;
                const size_t off = (size_t)cm * ldc + n;
                if (accumulate) v += C[off];
                if (add1) v += add1[off];
                if (add2) v += add2[off];
                C[off] = v;
            }
        }
    }
}

// ---------------------------------------------------------------- RoPE (in place)
__global__ __launch_bounds__(256)
void rope_k(float* __restrict__ p, int nheads)
{
    const int idx = blockIdx.x * 256 + threadIdx.x;
    const int total = TT * nheads * (DH / 2);
    if (idx >= total) return;
    const int i  = idx & 63;
    const int hh = (idx >> 6) % nheads;
    const int tt = idx / (64 * nheads);
    const int s  = tt & (SS - 1);      // position within sequence (S pow2)
    const float freq = expf(-(float)i * (9.210340371976184f / 64.f)); // 10000^{-i/64}
    const float ang = (float)s * freq;
    float sn, cs;
    sincosf(ang, &sn, &cs);
    float* base = p + ((size_t)tt * nheads + hh) * DH;
    const float x1 = base[i], x2 = base[i + 64];
    base[i]      = x1 * cs - x2 * sn;
    base[i + 64] = x2 * cs + x1 * sn;
}

// ---------------------------------------------------------------- flash attention
// Grid (S/64, NQ, B); 256 threads. 64 queries x 32-key tiles, causal, GQA (kv = hq>>3).
// K and V share one LDS tile (K during scores, V during PV) to fit 64KB static LDS.
static constexpr int QT   = 64;
static constexpr int KT   = 32;
static constexpr int QSTR = DH + 4;   // 132 floats: 16B-aligned rows, 2-way max conflicts

__global__ __launch_bounds__(256)
void attn_k(const float* __restrict__ qb, const float* __restrict__ kb,
            const float* __restrict__ vb, float* __restrict__ ob)
{
    __shared__ float Qs[QT][QSTR];
    __shared__ float KVs[KT][QSTR];
    __shared__ float Ps[QT][KT + 1];
    __shared__ float Mrow[QT];
    __shared__ float Lrow[QT];

    const int t   = threadIdx.x;
    const int q0  = blockIdx.x * QT;
    const int hq  = blockIdx.y;
    const int bz  = blockIdx.z;
    const int kvh = hq >> 3;                    // NQ/NKV = 8
    const float scl = 0.08838834764831845f;     // 1/sqrt(128)

    for (int i4 = t; i4 < QT * (DH / 4); i4 += 256) {
        const int qi = i4 >> 5, c4 = i4 & 31;
        float4 v = *((const float4*)(qb + ((size_t)(bz * SS + q0 + qi) * NQ + hq) * DH) + c4);
        v.x *= scl; v.y *= scl; v.z *= scl; v.w *= scl;
        *(float4*)&Qs[qi][c4 << 2] = v;
    }
    if (t < QT) { Mrow[t] = -1e30f; Lrow[t] = 0.f; }

    const int tr = t >> 4;   // query group: rows 4tr..4tr+3
    const int tc = t & 15;   // keys {tc, tc+16}; O cols {4tc..4tc+3, 64+4tc..}
    float O[4][8] = {};

    const int nk = q0 + QT;
    for (int k0 = 0; k0 < nk; k0 += KT) {
        float4 kreg[4], vreg[4];
#pragma unroll
        for (int i = 0; i < 4; ++i) {
            const int idx4 = t + (i << 8);
            const int kj = idx4 >> 5, c4 = idx4 & 31;
            const size_t roff = ((size_t)(bz * SS + k0 + kj) * NKV + kvh) * DH + (c4 << 2);
            kreg[i] = *(const float4*)(kb + roff);
            vreg[i] = *(const float4*)(vb + roff);
        }
        __syncthreads();                       // prior PV done with KVs/Ps
#pragma unroll
        for (int i = 0; i < 4; ++i) {
            const int idx4 = t + (i << 8);
            *(float4*)&KVs[idx4 >> 5][(idx4 & 31) << 2] = kreg[i];
        }
        __syncthreads();                       // K tile ready

        float s0[4] = {}, s1[4] = {};
#pragma unroll 8
        for (int d = 0; d < DH; d += 4) {
            const float4 ka = *(const float4*)&KVs[tc][d];
            const float4 kb4 = *(const float4*)&KVs[tc + 16][d];
#pragma unroll
            for (int i = 0; i < 4; ++i) {
                const float4 qv = *(const float4*)&Qs[(tr << 2) + i][d];
                s0[i] += qv.x * ka.x + qv.y * ka.y + qv.z * ka.z + qv.w * ka.w;
                s1[i] += qv.x * kb4.x + qv.y * kb4.y + qv.z * kb4.z + qv.w * kb4.w;
            }
        }

#pragma unroll
        for (int i = 0; i < 4; ++i) {
            const int qg = q0 + (tr << 2) + i;
            const float a  = (k0 + tc      <= qg) ? s0[i] : -1e30f;
            const float bq_ = (k0 + tc + 16 <= qg) ? s1[i] : -1e30f;
            float mt = fmaxf(a, bq_);
#pragma unroll
            for (int o = 1; o < 16; o <<= 1) mt = fmaxf(mt, __shfl_xor(mt, o, 64));
            const float mold = Mrow[(tr << 2) + i];
            const float mnew = fmaxf(mold, mt);
            const float alpha = __expf(mold - mnew);
            const float p0 = __expf(a - mnew);
            const float p1 = __expf(bq_ - mnew);
            float ls = p0 + p1;
#pragma unroll
            for (int o = 1; o < 16; o <<= 1) ls += __shfl_xor(ls, o, 64);
            if (tc == 0) {
                Mrow[(tr << 2) + i] = mnew;
                Lrow[(tr << 2) + i] = alpha * Lrow[(tr << 2) + i] + ls;
            }
            Ps[(tr << 2) + i][tc]      = p0;
            Ps[(tr << 2) + i][tc + 16] = p1;
#pragma unroll
            for (int j = 0; j < 8; ++j) O[i][j] *= alpha;
        }
        __syncthreads();                       // everyone done reading K
#pragma unroll
        for (int i = 0; i < 4; ++i) {
            const int idx4 = t + (i << 8);
            *(float4*)&KVs[idx4 >> 5][(idx4 & 31) << 2] = vreg[i];
        }
        __syncthreads();                       // V ready, Ps visible

#pragma unroll 4
        for (int kj = 0; kj < KT; ++kj) {
            const float4 v0 = *(const float4*)&KVs[kj][tc << 2];
            const float4 v1 = *(const float4*)&KVs[kj][64 + (tc << 2)];
#pragma unroll
            for (int i = 0; i < 4; ++i) {
                const float p = Ps[(tr << 2) + i][kj];
                O[i][0] += p * v0.x; O[i][1] += p * v0.y;
                O[i][2] += p * v0.z; O[i][3] += p * v0.w;
                O[i][4] += p * v1.x; O[i][5] += p * v1.y;
                O[i][6] += p * v1.z; O[i][7] += p * v1.w;
            }
        }
    }

#pragma unroll
    for (int i = 0; i < 4; ++i) {
        const int qi = (tr << 2) + i;
        const float inv = 1.f / Lrow[qi];
        float* base = ob + ((size_t)(bz * SS + q0 + qi) * NQ + hq) * DH;
        float4 o0, o1;
        o0.x = O[i][0] * inv; o0.y = O[i][1] * inv; o0.z = O[i][2] * inv; o0.w = O[i][3] * inv;
        o1.x = O[i][4] * inv; o1.y = O[i][5] * inv; o1.z = O[i][6] * inv; o1.w = O[i][7] * inv;
        *(float4*)(base + (tc << 2)) = o0;
        *(float4*)(base + 64 + (tc << 2)) = o1;
    }
}

// ---------------------------------------------------------------- router (+ shared sigmoid gate)
__global__ __launch_bounds__(256)
void router_k(const float* __restrict__ tb, const float* __restrict__ rw,
              const float* __restrict__ sgw, float* __restrict__ dw,
              float* __restrict__ gs)
{
    const int tok = blockIdx.x;
    const float* xr = tb + (size_t)tok * HH;
    float acc[EE] = {};
    float ag = 0.f;
    for (int h = threadIdx.x; h < HH; h += 256) {
        const float xv = xr[h];
        const float4 r0 = *(const float4*)(rw + (size_t)h * EE);
        const float4 r1 = *(const float4*)(rw + (size_t)h * EE + 4);
        acc[0] += xv * r0.x; acc[1] += xv * r0.y; acc[2] += xv * r0.z; acc[3] += xv * r0.w;
        acc[4] += xv * r1.x; acc[5] += xv * r1.y; acc[6] += xv * r1.z; acc[7] += xv * r1.w;
        ag += xv * sgw[h];
    }
#pragma unroll
    for (int e = 0; e < EE; ++e)
#pragma unroll
        for (int o = 32; o > 0; o >>= 1) acc[e] += __shfl_down(acc[e], o, 64);
#pragma unroll
    for (int o = 32; o > 0; o >>= 1) ag += __shfl_down(ag, o, 64);
    __shared__ float red[4][EE + 1];
    if ((threadIdx.x & 63) == 0) {
        const int w = threadIdx.x >> 6;
#pragma unroll
        for (int e = 0; e < EE; ++e) red[w][e] = acc[e];
        red[w][EE] = ag;
    }
    __syncthreads();
    if (threadIdx.x == 0) {
        float l[EE];
#pragma unroll
        for (int e = 0; e < EE; ++e) l[e] = red[0][e] + red[1][e] + red[2][e] + red[3][e];
        const float g = red[0][EE] + red[1][EE] + red[2][EE] + red[3][EE];
        gs[tok] = 1.f / (1.f + expf(-g));
        float m = l[0];
        for (int e = 1; e < EE; ++e) m = fmaxf(m, l[e]);
        float p[EE]; float sum = 0.f;
        for (int e = 0; e < EE; ++e) { p[e] = expf(l[e] - m); sum += p[e]; }
        for (int e = 0; e < EE; ++e) p[e] /= sum;
        bool used[EE] = {};
        float wsum = 0.f;
        for (int k = 0; k < KSEL; ++k) {       // top-4, ties -> lowest index (lax.top_k)
            int bi = 0; float bv = -1.f;
            for (int e = 0; e < EE; ++e)
                if (!used[e] && p[e] > bv) { bv = p[e]; bi = e; }
            used[bi] = true; wsum += bv;
        }
        for (int e = 0; e < EE; ++e)
            dw[(size_t)tok * EE + e] = used[e] ? p[e] / wsum : 0.f;
    }
}

// ---------------------------------------------------------------- sparse-MoE routing lists
// Fixed stride-TT list region per expert (sum of counts == TT*KSEL exactly).
__global__ void route_init_k(int* __restrict__ cnt)
{
    if (threadIdx.x < EE) cnt[threadIdx.x] = 0;
}

__global__ __launch_bounds__(256)
void route_fill_k(const float* __restrict__ dw, int* __restrict__ cnt,
                  int* __restrict__ tokidx, float* __restrict__ tokw)
{
    const int t = blockIdx.x * 256 + threadIdx.x;
    if (t >= TT) return;
#pragma unroll
    for (int e = 0; e < EE; ++e) {
        const float w = dw[(size_t)t * EE + e];
        if (w > 0.f) {
            const int pos = atomicAdd(cnt + e, 1);
            tokidx[e * TT + pos] = t;
            tokw[e * TT + pos]   = w;
        }
    }
}

// pad each expert's list to a multiple of 128 (GEMM M-tile) with -1 sentinels
__global__ void route_pad_k(const int* __restrict__ cnt, int* __restrict__ mpad,
                            int* __restrict__ tokidx)
{
    const int e = blockIdx.x;
    const int c = cnt[e];
    const int mp = (c + 127) & ~127;
    if (threadIdx.x == 0) mpad[e] = mp;
    for (int i = c + threadIdx.x; i < mp; i += 64) tokidx[e * TT + i] = -1;
}

// ---------------------------------------------------------------- silu(g)*u (*dw[token,e]), optional row limit
__global__ __launch_bounds__(256)
void silu_mul_k(float* __restrict__ g, const float* __restrict__ u,
                const float* __restrict__ dw, int ecol, int icols, int n,
                const int* __restrict__ mlim)
{
    const int idx = blockIdx.x * 256 + threadIdx.x;
    if (idx >= n) return;
    if (mlim && idx >= (*mlim) * icols) return;
    const float gv = g[idx];
    const float uv = u[idx];
    float v = gv / (1.f + __expf(-gv)) * uv;
    if (dw) v *= dw[(size_t)(idx / icols) * EE + ecol];
    g[idx] = v;
}

// ---------------------------------------------------------------- launcher
extern "C" void kernel_launch(void* const* d_in, const int* in_sizes, int n_in,
                              void* d_out, int out_size, void* d_ws, size_t ws_size,
                              hipStream_t stream)
{
    (void)in_sizes; (void)n_in; (void)out_size;
    const float* x   = (const float*)d_in[0];
    const float* ln1 = (const float*)d_in[1];
    const float* wq  = (const float*)d_in[2];
    const float* bq  = (const float*)d_in[3];
    const float* wk  = (const float*)d_in[4];
    const float* bk  = (const float*)d_in[5];
    const float* wv  = (const float*)d_in[6];
    const float* bv  = (const float*)d_in[7];
    const float* wo  = (const float*)d_in[8];
    const float* ln2 = (const float*)d_in[9];
    const float* rww = (const float*)d_in[10];
    const float* wg  = (const float*)d_in[11];
    const float* wu  = (const float*)d_in[12];
    const float* wd  = (const float*)d_in[13];
    const float* swg = (const float*)d_in[14];
    const float* swu = (const float*)d_in[15];
    const float* swd = (const float*)d_in[16];
    const float* sgw = (const float*)d_in[17];
    float* out = (float*)d_out;

    // workspace layout (f32); attnb aliases hbuf, tb aliases qb
    float* ws   = (float*)d_ws;
    float* hbuf = ws;
    float* qb   = hbuf + (size_t)TT * HH;
    float* kb   = qb   + (size_t)TT * NQ * DH;
    float* vb   = kb   + (size_t)TT * NKV * DH;
    float* x1   = vb   + (size_t)TT * NKV * DH;
    float* moe  = x1   + (size_t)TT * HH;
    float* gbuf = moe  + (size_t)TT * HH;
    float* ubuf = gbuf + (size_t)TT * IMOE;
    float* dw   = ubuf + (size_t)TT * IMOE;
    float* gs   = dw   + (size_t)TT * EE;
    int*   tokidx = (int*)(gs + TT);                 // [EE][TT]
    float* tokw   = (float*)(tokidx + (size_t)EE * TT); // [EE][TT]
    int*   cnt    = (int*)(tokw + (size_t)EE * TT);  // [EE]
    int*   mpad   = cnt + EE;                        // [EE]
    const size_t need_bytes = (size_t)((char*)(mpad + EE) - (char*)ws);
    if (ws_size < need_bytes) return;                // workspace too small

    float* attnb = hbuf;   // hbuf dead after q/k/v projections
    float* tb    = qb;     // qb dead after attention

    // 1) pre-norm
    rmsnorm_k<<<TT, 256, 0, stream>>>(x, ln1, hbuf);
    // 2) q/k/v projections (+bias)  [tiles are 128x128 now]
    gemm_k<<<dim3((NQ * DH) / 128, TT / 128), 256, 0, stream>>>(hbuf, HH, wq, NQ * DH, qb, NQ * DH, HH, bq, nullptr, nullptr, nullptr, 0, nullptr, nullptr, nullptr);
    gemm_k<<<dim3((NKV * DH) / 128, TT / 128), 256, 0, stream>>>(hbuf, HH, wk, NKV * DH, kb, NKV * DH, HH, bk, nullptr, nullptr, nullptr, 0, nullptr, nullptr, nullptr);
    gemm_k<<<dim3((NKV * DH) / 128, TT / 128), 256, 0, stream>>>(hbuf, HH, wv, NKV * DH, vb, NKV * DH, HH, bv, nullptr, nullptr, nullptr, 0, nullptr, nullptr, nullptr);
    // 3) RoPE
    rope_k<<<(TT * NQ * 64 + 255) / 256, 256, 0, stream>>>(qb, NQ);
    rope_k<<<(TT * NKV * 64 + 255) / 256, 256, 0, stream>>>(kb, NKV);
    // 4) causal GQA attention
    attn_k<<<dim3(SS / QT, NQ, BB), 256, 0, stream>>>(qb, kb, vb, attnb);
    // 5) output projection + residual
    gemm_k<<<dim3(HH / 128, TT / 128), 256, 0, stream>>>(attnb, NQ * DH, wo, HH, x1, HH, NQ * DH, nullptr, nullptr, x, nullptr, 0, nullptr, nullptr, nullptr);
    // 6) post-attn norm + router (+ shared sigmoid gate)
    rmsnorm_k<<<TT, 256, 0, stream>>>(x1, ln2, tb);
    router_k<<<TT, 256, 0, stream>>>(tb, rww, sgw, dw, gs);
    // 6b) sparse routing lists + zero the MoE accumulator
    zero_k<<<(TT * HH / 4 + 255) / 256, 256, 0, stream>>>(moe, TT * HH / 4);
    route_init_k<<<1, 64, 0, stream>>>(cnt);
    route_fill_k<<<(TT + 255) / 256, 256, 0, stream>>>(dw, cnt, tokidx, tokw);
    route_pad_k<<<EE, 64, 0, stream>>>(cnt, mpad, tokidx);
    // 7) experts — SPARSE: only tokens routed to expert e (avg ~T*K/E rows).
    //    gate/up gather A rows via tokidx; down scatter-accumulates into moe
    //    with per-row routing weight (matches reference: weight applied AFTER down-proj).
    const int nmoe = TT * IMOE;
    for (int e = 0; e < EE; ++e) {
        const float* wge = wg + (size_t)e * HH * IMOE;
        const float* wue = wu + (size_t)e * HH * IMOE;
        const float* wde = wd + (size_t)e * IMOE * HH;
        const int*   idx = tokidx + e * TT;
        const float* twe = tokw + e * TT;
        const int*   ml  = mpad + e;
        gemm_k<<<dim3(IMOE / 128, TT / 128), 256, 0, stream>>>(tb, HH, wge, IMOE, gbuf, IMOE, HH, nullptr, nullptr, nullptr, nullptr, 0, idx, nullptr, ml);
        gemm_k<<<dim3(IMOE / 128, TT / 128), 256, 0, stream>>>(tb, HH, wue, IMOE, ubuf, IMOE, HH, nullptr, nullptr, nullptr, nullptr, 0, idx, nullptr, ml);
        silu_mul_k<<<(nmoe + 255) / 256, 256, 0, stream>>>(gbuf, ubuf, nullptr, 0, IMOE, nmoe, ml);
        gemm_k<<<dim3(HH / 128, TT / 128), 256, 0, stream>>>(gbuf, IMOE, wde, HH, moe, HH, IMOE, nullptr, twe, nullptr, nullptr, 1, nullptr, idx, ml);
    }
    // 8) shared expert, chunked over I_SH in 4 x 1408; last chunk fuses final residual sum
    for (int c = 0; c < 4; ++c) {
        const float* swgc = swg + (size_t)c * IMOE;          // column block, ldb = ISH
        const float* swuc = swu + (size_t)c * IMOE;
        const float* swdc = swd + (size_t)c * IMOE * HH;     // row block
        gemm_k<<<dim3(IMOE / 128, TT / 128), 256, 0, stream>>>(tb, HH, swgc, ISH, gbuf, IMOE, HH, nullptr, nullptr, nullptr, nullptr, 0, nullptr, nullptr, nullptr);
        gemm_k<<<dim3(IMOE / 128, TT / 128), 256, 0, stream>>>(tb, HH, swuc, ISH, ubuf, IMOE, HH, nullptr, nullptr, nullptr, nullptr, 0, nullptr, nullptr, nullptr);
        silu_mul_k<<<(nmoe + 255) / 256, 256, 0, stream>>>(gbuf, ubuf, nullptr, 0, IMOE, nmoe, nullptr);
        if (c < 3)
            gemm_k<<<dim3(HH / 128, TT / 128), 256, 0, stream>>>(gbuf, IMOE, swdc, HH, moe, HH, IMOE, nullptr, gs, nullptr, nullptr, 1, nullptr, nullptr, nullptr);
        else  // out = x1 + moe + gs .* (hs_c @ swdown_c)
            gemm_k<<<dim3(HH / 128, TT / 128), 256, 0, stream>>>(gbuf, IMOE, swdc, HH, out, HH, IMOE, nullptr, gs, moe, x1, 0, nullptr, nullptr, nullptr);
    }
}

// Round 3
// 5921.076 us; speedup vs baseline: 2.1484x; 2.1484x over previous
//
#include <hip/hip_runtime.h>
#include <math.h>

// Problem constants (QwenMoeTransformerDecoder: B=2,S=2048,H=2048,E=8,K=4)
static constexpr int BB   = 2;
static constexpr int SS   = 2048;
static constexpr int HH   = 2048;
static constexpr int TT   = BB * SS;   // 4096 tokens
static constexpr int EE   = 8;
static constexpr int KSEL = 4;
static constexpr int IMOE = 1408;
static constexpr int ISH  = 5632;      // = 4 * IMOE (chunked)
static constexpr int NQ   = 16;
static constexpr int NKV  = 2;
static constexpr int DH   = 128;

typedef __attribute__((ext_vector_type(8))) short bhalf8;
typedef __attribute__((ext_vector_type(4))) float floatx4;

union U16B { uint4 u; bhalf8 s; };
__device__ __forceinline__ bhalf8 as_b8(uint4 u) { U16B x; x.u = u; return x.s; }

// split 8 consecutive f32 into hi/lo bf16 planes (truncation split: exact residual)
__device__ __forceinline__ void split_pack8(const float* f, uint4& hi, uint4& lo)
{
    unsigned h[4], lw[4];
#pragma unroll
    for (int q = 0; q < 4; ++q) {
        const float f0 = f[2 * q], f1 = f[2 * q + 1];
        const unsigned u0 = __float_as_uint(f0), u1 = __float_as_uint(f1);
        const unsigned m0 = u0 & 0xffff0000u, m1 = u1 & 0xffff0000u;
        h[q] = (u0 >> 16) | m1;
        const float l0 = f0 - __uint_as_float(m0);   // exact
        const float l1 = f1 - __uint_as_float(m1);   // exact
        lw[q] = (__float_as_uint(l0) >> 16) | (__float_as_uint(l1) & 0xffff0000u);
    }
    hi = make_uint4(h[0], h[1], h[2], h[3]);
    lo = make_uint4(lw[0], lw[1], lw[2], lw[3]);
}

// ---------------------------------------------------------------- RMSNorm
__global__ __launch_bounds__(256)
void rmsnorm_k(const float* __restrict__ x, const float* __restrict__ sc,
               float* __restrict__ o)
{
    const int row = blockIdx.x;
    const float4* xr = (const float4*)(x + (size_t)row * HH);
    const float4* sr = (const float4*)sc;
    float4* orow = (float4*)(o + (size_t)row * HH);
    float ss = 0.f;
    for (int i = threadIdx.x; i < HH / 4; i += 256) {
        float4 v = xr[i];
        ss += v.x * v.x + v.y * v.y + v.z * v.z + v.w * v.w;
    }
#pragma unroll
    for (int off = 32; off > 0; off >>= 1) ss += __shfl_down(ss, off, 64);
    __shared__ float red[4];
    if ((threadIdx.x & 63) == 0) red[threadIdx.x >> 6] = ss;
    __syncthreads();
    const float tot = red[0] + red[1] + red[2] + red[3];
    const float inv = rsqrtf(tot / (float)HH + 1e-5f);
    for (int i = threadIdx.x; i < HH / 4; i += 256) {
        float4 v = xr[i]; float4 s = sr[i];
        float4 w;
        w.x = v.x * inv * s.x; w.y = v.y * inv * s.y;
        w.z = v.z * inv * s.z; w.w = v.w * inv * s.w;
        orow[i] = w;
    }
}

// ---------------------------------------------------------------- zero fill (float4 granularity)
__global__ __launch_bounds__(256)
void zero_k(float* __restrict__ p, int n4)
{
    const int i = blockIdx.x * 256 + threadIdx.x;
    if (i < n4) ((float4*)p)[i] = make_float4(0.f, 0.f, 0.f, 0.f);
}

// ---------------------------------------------------------------- split-bf16 MFMA GEMM
// C[m,n] = dot(A[arow?arow[m]:m,:],B[:,n]) (+bias[n]), *rowscale[m], (+=C), (+add1), (+add2)
// f32 inputs are split on the fly into hi/lo bf16 planes; 3 MFMA passes
// (hi*hi + hi*lo + lo*hi) in f32 accumulators recover ~f32 precision
// ("3xTF32" scheme; dropped lo*lo ~2^-16 relative).
// 128x128 tile, K-step 32, 256 threads = 4 waves in 2x2, each wave 64x64 via
// 4x4 frags of v_mfma_f32_16x16x32_bf16.  LDS is fragment-linear 16B chunks
// (lane's 8-bf16 k-run), so all LDS I/O is linear b128, conflict-free.
// C/D lane map (m89-verified): col = lane&15, row = (lane>>4)*4 + reg.
__global__ __launch_bounds__(256)
void gemm_k(const float* __restrict__ A, int lda,
            const float* __restrict__ Bm, int ldb,
            float* __restrict__ C, int ldc, int K,
            const float* __restrict__ bias,
            const float* __restrict__ rowscale,
            const float* __restrict__ add1,
            const float* __restrict__ add2,
            int accumulate,
            const int* __restrict__ arow,
            const int* __restrict__ crow,
            const int* __restrict__ mlim)
{
    const int m0 = blockIdx.y * 128;
    if (mlim && m0 >= *mlim) return;       // uniform exit, before any barrier

    __shared__ uint4 lds[2048];            // Ahi[512] Alo[512] Bhi[512] Blo[512] = 32KB
    uint4* Ahi = lds;
    uint4* Alo = lds + 512;
    uint4* Bhi = lds + 1024;
    uint4* Blo = lds + 1536;

    const int t  = threadIdx.x;
    const int n0 = blockIdx.x * 128;

    // ---- staging coords: A rows 128 x k32 (16 f32/thread), B k32 x cols 128
    const int sar = t >> 1;            // 0..127  A tile row
    const int sak = (t & 1) << 4;      // 0/16    A k-offset
    const int sbc = t & 127;           // 0..127  B tile col
    const int sbk = (t >> 7) << 4;     // 0/16    B k-offset
    int arow_eff = m0 + sar;
    if (arow) { const int r = arow[arow_eff]; arow_eff = (r < 0) ? 0 : r; }
    const float* Ap = A + (size_t)arow_eff * lda + sak;
    const float* Bp = Bm + (size_t)sbk * ldb + n0 + sbc;
    // chunk slots: A chunk (fr,kg,r) = ((fr*4+kg)*16 + r); this thread owns kg = sak/8 + {0,1}
    const int aslot = ((sar >> 4) * 4 + (sak >> 3)) * 16 + (sar & 15);
    const int bslot = ((sbc >> 4) * 4 + (sbk >> 3)) * 16 + (sbc & 15);

    // ---- wave coords
    const int w  = t >> 6, l = t & 63;
    const int wr = w >> 1, wc = w & 1;     // 2x2 waves, each 64x64
    const int lr = l & 15, kg = l >> 4;    // frag lane coords

    floatx4 acc[4][4];
#pragma unroll
    for (int i = 0; i < 4; ++i)
#pragma unroll
        for (int j = 0; j < 4; ++j) acc[i][j] = (floatx4){0.f, 0.f, 0.f, 0.f};

    // raw f32 prefetch buffers (converted at store time)
    float af[16], bf[16];
    *(float4*)&af[0]  = *(const float4*)(Ap + 0);
    *(float4*)&af[4]  = *(const float4*)(Ap + 4);
    *(float4*)&af[8]  = *(const float4*)(Ap + 8);
    *(float4*)&af[12] = *(const float4*)(Ap + 12);
#pragma unroll
    for (int j = 0; j < 16; ++j) bf[j] = Bp[(size_t)j * ldb];

    for (int k0 = 0; k0 < K; k0 += 32) {
        __syncthreads();                   // previous frag reads done
        {
            uint4 h0, l0, h1, l1;
            split_pack8(&af[0], h0, l0);
            split_pack8(&af[8], h1, l1);
            Ahi[aslot] = h0; Ahi[aslot + 16] = h1;
            Alo[aslot] = l0; Alo[aslot + 16] = l1;
            split_pack8(&bf[0], h0, l0);
            split_pack8(&bf[8], h1, l1);
            Bhi[bslot] = h0; Bhi[bslot + 16] = h1;
            Blo[bslot] = l0; Blo[bslot + 16] = l1;
        }
        __syncthreads();                   // tile ready

        if (k0 + 32 < K) {                 // prefetch next tile (overlaps MFMA phase)
            const int kn = k0 + 32;
            *(float4*)&af[0]  = *(const float4*)(Ap + kn + 0);
            *(float4*)&af[4]  = *(const float4*)(Ap + kn + 4);
            *(float4*)&af[8]  = *(const float4*)(Ap + kn + 8);
            *(float4*)&af[12] = *(const float4*)(Ap + kn + 12);
#pragma unroll
            for (int j = 0; j < 16; ++j) bf[j] = Bp[(size_t)(kn + j) * ldb];
        }

        bhalf8 ah[4], al[4];
#pragma unroll
        for (int i = 0; i < 4; ++i) {
            const int s = ((wr * 4 + i) * 4 + kg) * 16 + lr;
            ah[i] = as_b8(Ahi[s]);
            al[i] = as_b8(Alo[s]);
        }
#pragma unroll
        for (int j = 0; j < 4; ++j) {
            const int s = ((wc * 4 + j) * 4 + kg) * 16 + lr;
            const bhalf8 bh = as_b8(Bhi[s]);
            const bhalf8 bl = as_b8(Blo[s]);
#pragma unroll
            for (int i = 0; i < 4; ++i) {
                acc[i][j] = __builtin_amdgcn_mfma_f32_16x16x32_bf16(ah[i], bl, acc[i][j], 0, 0, 0);
                acc[i][j] = __builtin_amdgcn_mfma_f32_16x16x32_bf16(al[i], bh, acc[i][j], 0, 0, 0);
                acc[i][j] = __builtin_amdgcn_mfma_f32_16x16x32_bf16(ah[i], bh, acc[i][j], 0, 0, 0);
            }
        }
    }

    // ---- epilogue: C/D map col=lane&15, row=(lane>>4)*4+reg
#pragma unroll
    for (int i = 0; i < 4; ++i) {
#pragma unroll
        for (int q = 0; q < 4; ++q) {
            const int m = m0 + (wr * 4 + i) * 16 + kg * 4 + q;
            int cm = m;
            if (crow) { cm = crow[m]; if (cm < 0) continue; }
            const float rs = rowscale ? rowscale[m] : 1.f;
#pragma unroll
            for (int j = 0; j < 4; ++j) {
                const int n = n0 + (wc * 4 + j) * 16 + lr;
                float v = acc[i][j][q];
                if (bias) v += bias[n];
                v *= rs;
                const size_t off = (size_t)cm * ldc + n;
                if (accumulate) v += C[off];
                if (add1) v += add1[off];
                if (add2) v += add2[off];
                C[off] = v;
            }
        }
    }
}

// ---------------------------------------------------------------- RoPE (in place)
__global__ __launch_bounds__(256)
void rope_k(float* __restrict__ p, int nheads)
{
    const int idx = blockIdx.x * 256 + threadIdx.x;
    const int total = TT * nheads * (DH / 2);
    if (idx >= total) return;
    const int i  = idx & 63;
    const int hh = (idx >> 6) % nheads;
    const int tt = idx / (64 * nheads);
    const int s  = tt & (SS - 1);      // position within sequence (S pow2)
    const float freq = expf(-(float)i * (9.210340371976184f / 64.f)); // 10000^{-i/64}
    const float ang = (float)s * freq;
    float sn, cs;
    sincosf(ang, &sn, &cs);
    float* base = p + ((size_t)tt * nheads + hh) * DH;
    const float x1 = base[i], x2 = base[i + 64];
    base[i]      = x1 * cs - x2 * sn;
    base[i + 64] = x2 * cs + x1 * sn;
}

// ---------------------------------------------------------------- flash attention
// Grid (S/64, NQ, B); 256 threads. 64 queries x 32-key tiles, causal, GQA (kv = hq>>3).
// K and V share one LDS tile (K during scores, V during PV) to fit 64KB static LDS.
static constexpr int QT   = 64;
static constexpr int KT   = 32;
static constexpr int QSTR = DH + 4;   // 132 floats: 16B-aligned rows, 2-way max conflicts

__global__ __launch_bounds__(256)
void attn_k(const float* __restrict__ qb, const float* __restrict__ kb,
            const float* __restrict__ vb, float* __restrict__ ob)
{
    __shared__ float Qs[QT][QSTR];
    __shared__ float KVs[KT][QSTR];
    __shared__ float Ps[QT][KT + 1];
    __shared__ float Mrow[QT];
    __shared__ float Lrow[QT];

    const int t   = threadIdx.x;
    const int q0  = blockIdx.x * QT;
    const int hq  = blockIdx.y;
    const int bz  = blockIdx.z;
    const int kvh = hq >> 3;                    // NQ/NKV = 8
    const float scl = 0.08838834764831845f;     // 1/sqrt(128)

    for (int i4 = t; i4 < QT * (DH / 4); i4 += 256) {
        const int qi = i4 >> 5, c4 = i4 & 31;
        float4 v = *((const float4*)(qb + ((size_t)(bz * SS + q0 + qi) * NQ + hq) * DH) + c4);
        v.x *= scl; v.y *= scl; v.z *= scl; v.w *= scl;
        *(float4*)&Qs[qi][c4 << 2] = v;
    }
    if (t < QT) { Mrow[t] = -1e30f; Lrow[t] = 0.f; }

    const int tr = t >> 4;   // query group: rows 4tr..4tr+3
    const int tc = t & 15;   // keys {tc, tc+16}; O cols {4tc..4tc+3, 64+4tc..}
    float O[4][8] = {};

    const int nk = q0 + QT;
    for (int k0 = 0; k0 < nk; k0 += KT) {
        float4 kreg[4], vreg[4];
#pragma unroll
        for (int i = 0; i < 4; ++i) {
            const int idx4 = t + (i << 8);
            const int kj = idx4 >> 5, c4 = idx4 & 31;
            const size_t roff = ((size_t)(bz * SS + k0 + kj) * NKV + kvh) * DH + (c4 << 2);
            kreg[i] = *(const float4*)(kb + roff);
            vreg[i] = *(const float4*)(vb + roff);
        }
        __syncthreads();                       // prior PV done with KVs/Ps
#pragma unroll
        for (int i = 0; i < 4; ++i) {
            const int idx4 = t + (i << 8);
            *(float4*)&KVs[idx4 >> 5][(idx4 & 31) << 2] = kreg[i];
        }
        __syncthreads();                       // K tile ready

        float s0[4] = {}, s1[4] = {};
#pragma unroll 8
        for (int d = 0; d < DH; d += 4) {
            const float4 ka = *(const float4*)&KVs[tc][d];
            const float4 kb4 = *(const float4*)&KVs[tc + 16][d];
#pragma unroll
            for (int i = 0; i < 4; ++i) {
                const float4 qv = *(const float4*)&Qs[(tr << 2) + i][d];
                s0[i] += qv.x * ka.x + qv.y * ka.y + qv.z * ka.z + qv.w * ka.w;
                s1[i] += qv.x * kb4.x + qv.y * kb4.y + qv.z * kb4.z + qv.w * kb4.w;
            }
        }

#pragma unroll
        for (int i = 0; i < 4; ++i) {
            const int qg = q0 + (tr << 2) + i;
            const float a  = (k0 + tc      <= qg) ? s0[i] : -1e30f;
            const float bq_ = (k0 + tc + 16 <= qg) ? s1[i] : -1e30f;
            float mt = fmaxf(a, bq_);
#pragma unroll
            for (int o = 1; o < 16; o <<= 1) mt = fmaxf(mt, __shfl_xor(mt, o, 64));
            const float mold = Mrow[(tr << 2) + i];
            const float mnew = fmaxf(mold, mt);
            const float alpha = __expf(mold - mnew);
            const float p0 = __expf(a - mnew);
            const float p1 = __expf(bq_ - mnew);
            float ls = p0 + p1;
#pragma unroll
            for (int o = 1; o < 16; o <<= 1) ls += __shfl_xor(ls, o, 64);
            if (tc == 0) {
                Mrow[(tr << 2) + i] = mnew;
                Lrow[(tr << 2) + i] = alpha * Lrow[(tr << 2) + i] + ls;
            }
            Ps[(tr << 2) + i][tc]      = p0;
            Ps[(tr << 2) + i][tc + 16] = p1;
#pragma unroll
            for (int j = 0; j < 8; ++j) O[i][j] *= alpha;
        }
        __syncthreads();                       // everyone done reading K
#pragma unroll
        for (int i = 0; i < 4; ++i) {
            const int idx4 = t + (i << 8);
            *(float4*)&KVs[idx4 >> 5][(idx4 & 31) << 2] = vreg[i];
        }
        __syncthreads();                       // V ready, Ps visible

#pragma unroll 4
        for (int kj = 0; kj < KT; ++kj) {
            const float4 v0 = *(const float4*)&KVs[kj][tc << 2];
            const float4 v1 = *(const float4*)&KVs[kj][64 + (tc << 2)];
#pragma unroll
            for (int i = 0; i < 4; ++i) {
                const float p = Ps[(tr << 2) + i][kj];
                O[i][0] += p * v0.x; O[i][1] += p * v0.y;
                O[i][2] += p * v0.z; O[i][3] += p * v0.w;
                O[i][4] += p * v1.x; O[i][5] += p * v1.y;
                O[i][6] += p * v1.z; O[i][7] += p * v1.w;
            }
        }
    }

#pragma unroll
    for (int i = 0; i < 4; ++i) {
        const int qi = (tr << 2) + i;
        const float inv = 1.f / Lrow[qi];
        float* base = ob + ((size_t)(bz * SS + q0 + qi) * NQ + hq) * DH;
        float4 o0, o1;
        o0.x = O[i][0] * inv; o0.y = O[i][1] * inv; o0.z = O[i][2] * inv; o0.w = O[i][3] * inv;
        o1.x = O[i][4] * inv; o1.y = O[i][5] * inv; o1.z = O[i][6] * inv; o1.w = O[i][7] * inv;
        *(float4*)(base + (tc << 2)) = o0;
        *(float4*)(base + 64 + (tc << 2)) = o1;
    }
}

// ---------------------------------------------------------------- router (+ shared sigmoid gate)
__global__ __launch_bounds__(256)
void router_k(const float* __restrict__ tb, const float* __restrict__ rw,
              const float* __restrict__ sgw, float* __restrict__ dw,
              float* __restrict__ gs)
{
    const int tok = blockIdx.x;
    const float* xr = tb + (size_t)tok * HH;
    float acc[EE] = {};
    float ag = 0.f;
    for (int h = threadIdx.x; h < HH; h += 256) {
        const float xv = xr[h];
        const float4 r0 = *(const float4*)(rw + (size_t)h * EE);
        const float4 r1 = *(const float4*)(rw + (size_t)h * EE + 4);
        acc[0] += xv * r0.x; acc[1] += xv * r0.y; acc[2] += xv * r0.z; acc[3] += xv * r0.w;
        acc[4] += xv * r1.x; acc[5] += xv * r1.y; acc[6] += xv * r1.z; acc[7] += xv * r1.w;
        ag += xv * sgw[h];
    }
#pragma unroll
    for (int e = 0; e < EE; ++e)
#pragma unroll
        for (int o = 32; o > 0; o >>= 1) acc[e] += __shfl_down(acc[e], o, 64);
#pragma unroll
    for (int o = 32; o > 0; o >>= 1) ag += __shfl_down(ag, o, 64);
    __shared__ float red[4][EE + 1];
    if ((threadIdx.x & 63) == 0) {
        const int w = threadIdx.x >> 6;
#pragma unroll
        for (int e = 0; e < EE; ++e) red[w][e] = acc[e];
        red[w][EE] = ag;
    }
    __syncthreads();
    if (threadIdx.x == 0) {
        float l[EE];
#pragma unroll
        for (int e = 0; e < EE; ++e) l[e] = red[0][e] + red[1][e] + red[2][e] + red[3][e];
        const float g = red[0][EE] + red[1][EE] + red[2][EE] + red[3][EE];
        gs[tok] = 1.f / (1.f + expf(-g));
        float m = l[0];
        for (int e = 1; e < EE; ++e) m = fmaxf(m, l[e]);
        float p[EE]; float sum = 0.f;
        for (int e = 0; e < EE; ++e) { p[e] = expf(l[e] - m); sum += p[e]; }
        for (int e = 0; e < EE; ++e) p[e] /= sum;
        bool used[EE] = {};
        float wsum = 0.f;
        for (int k = 0; k < KSEL; ++k) {       // top-4, ties -> lowest index (lax.top_k)
            int bi = 0; float bv = -1.f;
            for (int e = 0; e < EE; ++e)
                if (!used[e] && p[e] > bv) { bv = p[e]; bi = e; }
            used[bi] = true; wsum += bv;
        }
        for (int e = 0; e < EE; ++e)
            dw[(size_t)tok * EE + e] = used[e] ? p[e] / wsum : 0.f;
    }
}

// ---------------------------------------------------------------- sparse-MoE routing lists
// Fixed stride-TT list region per expert (sum of counts == TT*KSEL exactly).
__global__ void route_init_k(int* __restrict__ cnt)
{
    if (threadIdx.x < EE) cnt[threadIdx.x] = 0;
}

__global__ __launch_bounds__(256)
void route_fill_k(const float* __restrict__ dw, int* __restrict__ cnt,
                  int* __restrict__ tokidx, float* __restrict__ tokw)
{
    const int t = blockIdx.x * 256 + threadIdx.x;
    if (t >= TT) return;
#pragma unroll
    for (int e = 0; e < EE; ++e) {
        const float w = dw[(size_t)t * EE + e];
        if (w > 0.f) {
            const int pos = atomicAdd(cnt + e, 1);
            tokidx[e * TT + pos] = t;
            tokw[e * TT + pos]   = w;
        }
    }
}

// pad each expert's list to a multiple of 128 (GEMM M-tile) with -1 sentinels
__global__ void route_pad_k(const int* __restrict__ cnt, int* __restrict__ mpad,
                            int* __restrict__ tokidx)
{
    const int e = blockIdx.x;
    const int c = cnt[e];
    const int mp = (c + 127) & ~127;
    if (threadIdx.x == 0) mpad[e] = mp;
    for (int i = c + threadIdx.x; i < mp; i += 64) tokidx[e * TT + i] = -1;
}

// ---------------------------------------------------------------- silu(g)*u (*dw[token,e]), optional row limit
__global__ __launch_bounds__(256)
void silu_mul_k(float* __restrict__ g, const float* __restrict__ u,
                const float* __restrict__ dw, int ecol, int icols, int n,
                const int* __restrict__ mlim)
{
    const int idx = blockIdx.x * 256 + threadIdx.x;
    if (idx >= n) return;
    if (mlim && idx >= (*mlim) * icols) return;
    const float gv = g[idx];
    const float uv = u[idx];
    float v = gv / (1.f + __expf(-gv)) * uv;
    if (dw) v *= dw[(size_t)(idx / icols) * EE + ecol];
    g[idx] = v;
}

// ---------------------------------------------------------------- launcher
extern "C" void kernel_launch(void* const* d_in, const int* in_sizes, int n_in,
                              void* d_out, int out_size, void* d_ws, size_t ws_size,
                              hipStream_t stream)
{
    (void)in_sizes; (void)n_in; (void)out_size;
    const float* x   = (const float*)d_in[0];
    const float* ln1 = (const float*)d_in[1];
    const float* wq  = (const float*)d_in[2];
    const float* bq  = (const float*)d_in[3];
    const float* wk  = (const float*)d_in[4];
    const float* bk  = (const float*)d_in[5];
    const float* wv  = (const float*)d_in[6];
    const float* bv  = (const float*)d_in[7];
    const float* wo  = (const float*)d_in[8];
    const float* ln2 = (const float*)d_in[9];
    const float* rww = (const float*)d_in[10];
    const float* wg  = (const float*)d_in[11];
    const float* wu  = (const float*)d_in[12];
    const float* wd  = (const float*)d_in[13];
    const float* swg = (const float*)d_in[14];
    const float* swu = (const float*)d_in[15];
    const float* swd = (const float*)d_in[16];
    const float* sgw = (const float*)d_in[17];
    float* out = (float*)d_out;

    // workspace layout (f32); attnb aliases hbuf, tb aliases qb
    float* ws   = (float*)d_ws;
    float* hbuf = ws;
    float* qb   = hbuf + (size_t)TT * HH;
    float* kb   = qb   + (size_t)TT * NQ * DH;
    float* vb   = kb   + (size_t)TT * NKV * DH;
    float* x1   = vb   + (size_t)TT * NKV * DH;
    float* moe  = x1   + (size_t)TT * HH;
    float* gbuf = moe  + (size_t)TT * HH;
    float* ubuf = gbuf + (size_t)TT * IMOE;
    float* dw   = ubuf + (size_t)TT * IMOE;
    float* gs   = dw   + (size_t)TT * EE;
    int*   tokidx = (int*)(gs + TT);                 // [EE][TT]
    float* tokw   = (float*)(tokidx + (size_t)EE * TT); // [EE][TT]
    int*   cnt    = (int*)(tokw + (size_t)EE * TT);  // [EE]
    int*   mpad   = cnt + EE;                        // [EE]
    const size_t need_bytes = (size_t)((char*)(mpad + EE) - (char*)ws);
    if (ws_size < need_bytes) return;                // workspace too small

    float* attnb = hbuf;   // hbuf dead after q/k/v projections
    float* tb    = qb;     // qb dead after attention

    // 1) pre-norm
    rmsnorm_k<<<TT, 256, 0, stream>>>(x, ln1, hbuf);
    // 2) q/k/v projections (+bias)
    gemm_k<<<dim3((NQ * DH) / 128, TT / 128), 256, 0, stream>>>(hbuf, HH, wq, NQ * DH, qb, NQ * DH, HH, bq, nullptr, nullptr, nullptr, 0, nullptr, nullptr, nullptr);
    gemm_k<<<dim3((NKV * DH) / 128, TT / 128), 256, 0, stream>>>(hbuf, HH, wk, NKV * DH, kb, NKV * DH, HH, bk, nullptr, nullptr, nullptr, 0, nullptr, nullptr, nullptr);
    gemm_k<<<dim3((NKV * DH) / 128, TT / 128), 256, 0, stream>>>(hbuf, HH, wv, NKV * DH, vb, NKV * DH, HH, bv, nullptr, nullptr, nullptr, 0, nullptr, nullptr, nullptr);
    // 3) RoPE
    rope_k<<<(TT * NQ * 64 + 255) / 256, 256, 0, stream>>>(qb, NQ);
    rope_k<<<(TT * NKV * 64 + 255) / 256, 256, 0, stream>>>(kb, NKV);
    // 4) causal GQA attention
    attn_k<<<dim3(SS / QT, NQ, BB), 256, 0, stream>>>(qb, kb, vb, attnb);
    // 5) output projection + residual
    gemm_k<<<dim3(HH / 128, TT / 128), 256, 0, stream>>>(attnb, NQ * DH, wo, HH, x1, HH, NQ * DH, nullptr, nullptr, x, nullptr, 0, nullptr, nullptr, nullptr);
    // 6) post-attn norm + router (+ shared sigmoid gate)
    rmsnorm_k<<<TT, 256, 0, stream>>>(x1, ln2, tb);
    router_k<<<TT, 256, 0, stream>>>(tb, rww, sgw, dw, gs);
    // 6b) sparse routing lists + zero the MoE accumulator
    zero_k<<<(TT * HH / 4 + 255) / 256, 256, 0, stream>>>(moe, TT * HH / 4);
    route_init_k<<<1, 64, 0, stream>>>(cnt);
    route_fill_k<<<(TT + 255) / 256, 256, 0, stream>>>(dw, cnt, tokidx, tokw);
    route_pad_k<<<EE, 64, 0, stream>>>(cnt, mpad, tokidx);
    // 7) experts — SPARSE: only tokens routed to expert e (avg ~T*K/E rows).
    //    gate/up gather A rows via tokidx; down scatter-accumulates into moe
    //    with per-row routing weight (matches reference: weight applied AFTER down-proj).
    const int nmoe = TT * IMOE;
    for (int e = 0; e < EE; ++e) {
        const float* wge = wg + (size_t)e * HH * IMOE;
        const float* wue = wu + (size_t)e * HH * IMOE;
        const float* wde = wd + (size_t)e * IMOE * HH;
        const int*   idx = tokidx + e * TT;
        const float* twe = tokw + e * TT;
        const int*   ml  = mpad + e;
        gemm_k<<<dim3(IMOE / 128, TT / 128), 256, 0, stream>>>(tb, HH, wge, IMOE, gbuf, IMOE, HH, nullptr, nullptr, nullptr, nullptr, 0, idx, nullptr, ml);
        gemm_k<<<dim3(IMOE / 128, TT / 128), 256, 0, stream>>>(tb, HH, wue, IMOE, ubuf, IMOE, HH, nullptr, nullptr, nullptr, nullptr, 0, idx, nullptr, ml);
        silu_mul_k<<<(nmoe + 255) / 256, 256, 0, stream>>>(gbuf, ubuf, nullptr, 0, IMOE, nmoe, ml);
        gemm_k<<<dim3(HH / 128, TT / 128), 256, 0, stream>>>(gbuf, IMOE, wde, HH, moe, HH, IMOE, nullptr, twe, nullptr, nullptr, 1, nullptr, idx, ml);
    }
    // 8) shared expert, chunked over I_SH in 4 x 1408; last chunk fuses final residual sum
    for (int c = 0; c < 4; ++c) {
        const float* swgc = swg + (size_t)c * IMOE;          // column block, ldb = ISH
        const float* swuc = swu + (size_t)c * IMOE;
        const float* swdc = swd + (size_t)c * IMOE * HH;     // row block
        gemm_k<<<dim3(IMOE / 128, TT / 128), 256, 0, stream>>>(tb, HH, swgc, ISH, gbuf, IMOE, HH, nullptr, nullptr, nullptr, nullptr, 0, nullptr, nullptr, nullptr);
        gemm_k<<<dim3(IMOE / 128, TT / 128), 256, 0, stream>>>(tb, HH, swuc, ISH, ubuf, IMOE, HH, nullptr, nullptr, nullptr, nullptr, 0, nullptr, nullptr, nullptr);
        silu_mul_k<<<(nmoe + 255) / 256, 256, 0, stream>>>(gbuf, ubuf, nullptr, 0, IMOE, nmoe, nullptr);
        if (c < 3)
            gemm_k<<<dim3(HH / 128, TT / 128), 256, 0, stream>>>(gbuf, IMOE, swdc, HH, moe, HH, IMOE, nullptr, gs, nullptr, nullptr, 1, nullptr, nullptr, nullptr);
        else  // out = x1 + moe + gs .* (hs_c @ swdown_c)
            gemm_k<<<dim3(HH / 128, TT / 128), 256, 0, stream>>>(gbuf, IMOE, swdc, HH, out, HH, IMOE, nullptr, gs, moe, x1, 0, nullptr, nullptr, nullptr);
    }
}

// Round 4
// 5905.282 us; speedup vs baseline: 2.1542x; 1.0027x over previous
//
#include <hip/hip_runtime.h>
#include <math.h>

// Problem constants (QwenMoeTransformerDecoder: B=2,S=2048,H=2048,E=8,K=4)
static constexpr int BB   = 2;
static constexpr int SS   = 2048;
static constexpr int HH   = 2048;
static constexpr int TT   = BB * SS;   // 4096 tokens
static constexpr int EE   = 8;
static constexpr int KSEL = 4;
static constexpr int IMOE = 1408;
static constexpr int ISH  = 5632;      // = 4 * IMOE (chunked)
static constexpr int NQ   = 16;
static constexpr int NKV  = 2;
static constexpr int DH   = 128;

typedef __attribute__((ext_vector_type(8))) short bhalf8;
typedef __attribute__((ext_vector_type(4))) float floatx4;

union U16B { uint4 u; bhalf8 s; };
__device__ __forceinline__ bhalf8 as_b8(uint4 u) { U16B x; x.u = u; return x.s; }

// split 8 consecutive f32 into hi/lo bf16 planes (truncation split: exact residual)
__device__ __forceinline__ void split_pack8(const float* f, uint4& hi, uint4& lo)
{
    unsigned h[4], lw[4];
#pragma unroll
    for (int q = 0; q < 4; ++q) {
        const float f0 = f[2 * q], f1 = f[2 * q + 1];
        const unsigned u0 = __float_as_uint(f0), u1 = __float_as_uint(f1);
        const unsigned m0 = u0 & 0xffff0000u, m1 = u1 & 0xffff0000u;
        h[q] = (u0 >> 16) | m1;
        const float l0 = f0 - __uint_as_float(m0);   // exact
        const float l1 = f1 - __uint_as_float(m1);   // exact
        lw[q] = (__float_as_uint(l0) >> 16) | (__float_as_uint(l1) & 0xffff0000u);
    }
    hi = make_uint4(h[0], h[1], h[2], h[3]);
    lo = make_uint4(lw[0], lw[1], lw[2], lw[3]);
}

// ---------------------------------------------------------------- RMSNorm
__global__ __launch_bounds__(256)
void rmsnorm_k(const float* __restrict__ x, const float* __restrict__ sc,
               float* __restrict__ o)
{
    const int row = blockIdx.x;
    const float4* xr = (const float4*)(x + (size_t)row * HH);
    const float4* sr = (const float4*)sc;
    float4* orow = (float4*)(o + (size_t)row * HH);
    float ss = 0.f;
    for (int i = threadIdx.x; i < HH / 4; i += 256) {
        float4 v = xr[i];
        ss += v.x * v.x + v.y * v.y + v.z * v.z + v.w * v.w;
    }
#pragma unroll
    for (int off = 32; off > 0; off >>= 1) ss += __shfl_down(ss, off, 64);
    __shared__ float red[4];
    if ((threadIdx.x & 63) == 0) red[threadIdx.x >> 6] = ss;
    __syncthreads();
    const float tot = red[0] + red[1] + red[2] + red[3];
    const float inv = rsqrtf(tot / (float)HH + 1e-5f);
    for (int i = threadIdx.x; i < HH / 4; i += 256) {
        float4 v = xr[i]; float4 s = sr[i];
        float4 w;
        w.x = v.x * inv * s.x; w.y = v.y * inv * s.y;
        w.z = v.z * inv * s.z; w.w = v.w * inv * s.w;
        orow[i] = w;
    }
}

// ---------------------------------------------------------------- zero fill (float4 granularity)
__global__ __launch_bounds__(256)
void zero_k(float* __restrict__ p, int n4)
{
    const int i = blockIdx.x * 256 + threadIdx.x;
    if (i < n4) ((float4*)p)[i] = make_float4(0.f, 0.f, 0.f, 0.f);
}

// ---------------------------------------------------------------- weight transpose+split
// W f32 [K][N] row-major  ->  th/tl bf16 planes [N][K] (truncation split,
// bit-identical to split_pack8).  64x64 tiles, blockIdx.z batches experts.
__global__ __launch_bounds__(256)
void splitw_k(const float* __restrict__ W, int K, int N,
              unsigned short* __restrict__ th, unsigned short* __restrict__ tl)
{
    const size_t zoff = (size_t)blockIdx.z * K * N;
    W += zoff; th += zoff; tl += zoff;
    __shared__ float tile[64][65];
    const int k0 = blockIdx.y * 64;
    const int n0 = blockIdx.x * 64;
    const int t  = threadIdx.x;
    const int c  = t & 63, rq = t >> 6;
#pragma unroll
    for (int r = 0; r < 16; ++r) {
        const int kk = r * 4 + rq;
        tile[kk][c] = W[(size_t)(k0 + kk) * N + n0 + c];
    }
    __syncthreads();
#pragma unroll
    for (int r = 0; r < 16; ++r) {
        const int nn = r * 4 + rq;
        const float v = tile[c][nn];                  // = W[k0+c][n0+nn]
        const unsigned u  = __float_as_uint(v);
        const unsigned hm = u & 0xffff0000u;
        const float lo = v - __uint_as_float(hm);     // exact
        th[(size_t)(n0 + nn) * K + k0 + c] = (unsigned short)(u >> 16);
        tl[(size_t)(n0 + nn) * K + k0 + c] = (unsigned short)(__float_as_uint(lo) >> 16);
    }
}

// ---------------------------------------------------------------- split-bf16 MFMA GEMM (plane-B)
// Same math/order as gemm_f_k, but B comes from pre-split transposed planes
// Bt[n][k] (hi/lo bf16): staging is 4 contiguous uint4 loads, zero split VALU.
// A stays f32 (split in-loop) so arow-gather keeps working.
__global__ __launch_bounds__(256)
void gemm_p_k(const float* __restrict__ A, int lda,
              const unsigned short* __restrict__ Bth,
              const unsigned short* __restrict__ Btl, int ldbt,
              float* __restrict__ C, int ldc, int K,
              const float* __restrict__ bias,
              const float* __restrict__ rowscale,
              const float* __restrict__ add1,
              const float* __restrict__ add2,
              int accumulate,
              const int* __restrict__ arow,
              const int* __restrict__ crow,
              const int* __restrict__ mlim)
{
    const int m0 = blockIdx.y * 128;
    if (mlim && m0 >= *mlim) return;       // uniform exit, before any barrier

    __shared__ uint4 lds[2048];            // Ahi[512] Alo[512] Bhi[512] Blo[512] = 32KB
    uint4* Ahi = lds;
    uint4* Alo = lds + 512;
    uint4* Bhi = lds + 1024;
    uint4* Blo = lds + 1536;

    const int t  = threadIdx.x;
    const int n0 = blockIdx.x * 128;

    const int sar = t >> 1;            // 0..127  A tile row
    const int sak = (t & 1) << 4;      // 0/16    A k-offset
    const int sbc = t & 127;           // 0..127  B tile col
    const int sbk = (t >> 7) << 4;     // 0/16    B k-offset
    int arow_eff = m0 + sar;
    if (arow) { const int r = arow[arow_eff]; arow_eff = (r < 0) ? 0 : r; }
    const float* Ap = A + (size_t)arow_eff * lda + sak;
    const unsigned short* Bph = Bth + (size_t)(n0 + sbc) * ldbt + sbk;
    const unsigned short* Bpl = Btl + (size_t)(n0 + sbc) * ldbt + sbk;
    const int aslot = ((sar >> 4) * 4 + (sak >> 3)) * 16 + (sar & 15);
    const int bslot = ((sbc >> 4) * 4 + (sbk >> 3)) * 16 + (sbc & 15);

    const int w  = t >> 6, l = t & 63;
    const int wr = w >> 1, wc = w & 1;     // 2x2 waves, each 64x64
    const int lr = l & 15, kg = l >> 4;    // frag lane coords

    floatx4 acc[4][4];
#pragma unroll
    for (int i = 0; i < 4; ++i)
#pragma unroll
        for (int j = 0; j < 4; ++j) acc[i][j] = (floatx4){0.f, 0.f, 0.f, 0.f};

    float af[16];
    uint4 rbh0, rbh1, rbl0, rbl1;
    *(float4*)&af[0]  = *(const float4*)(Ap + 0);
    *(float4*)&af[4]  = *(const float4*)(Ap + 4);
    *(float4*)&af[8]  = *(const float4*)(Ap + 8);
    *(float4*)&af[12] = *(const float4*)(Ap + 12);
    rbh0 = *(const uint4*)(Bph);
    rbh1 = *(const uint4*)(Bph + 8);
    rbl0 = *(const uint4*)(Bpl);
    rbl1 = *(const uint4*)(Bpl + 8);

    for (int k0 = 0; k0 < K; k0 += 32) {
        __syncthreads();                   // previous frag reads done
        {
            uint4 h0, l0, h1, l1;
            split_pack8(&af[0], h0, l0);
            split_pack8(&af[8], h1, l1);
            Ahi[aslot] = h0; Ahi[aslot + 16] = h1;
            Alo[aslot] = l0; Alo[aslot + 16] = l1;
            Bhi[bslot] = rbh0; Bhi[bslot + 16] = rbh1;
            Blo[bslot] = rbl0; Blo[bslot + 16] = rbl1;
        }
        __syncthreads();                   // tile ready

        if (k0 + 32 < K) {                 // prefetch next tile (overlaps MFMA phase)
            const int kn = k0 + 32;
            *(float4*)&af[0]  = *(const float4*)(Ap + kn + 0);
            *(float4*)&af[4]  = *(const float4*)(Ap + kn + 4);
            *(float4*)&af[8]  = *(const float4*)(Ap + kn + 8);
            *(float4*)&af[12] = *(const float4*)(Ap + kn + 12);
            rbh0 = *(const uint4*)(Bph + kn);
            rbh1 = *(const uint4*)(Bph + kn + 8);
            rbl0 = *(const uint4*)(Bpl + kn);
            rbl1 = *(const uint4*)(Bpl + kn + 8);
        }

        bhalf8 ah[4], al[4];
#pragma unroll
        for (int i = 0; i < 4; ++i) {
            const int s = ((wr * 4 + i) * 4 + kg) * 16 + lr;
            ah[i] = as_b8(Ahi[s]);
            al[i] = as_b8(Alo[s]);
        }
#pragma unroll
        for (int j = 0; j < 4; ++j) {
            const int s = ((wc * 4 + j) * 4 + kg) * 16 + lr;
            const bhalf8 bh = as_b8(Bhi[s]);
            const bhalf8 bl = as_b8(Blo[s]);
#pragma unroll
            for (int i = 0; i < 4; ++i) {
                acc[i][j] = __builtin_amdgcn_mfma_f32_16x16x32_bf16(ah[i], bl, acc[i][j], 0, 0, 0);
                acc[i][j] = __builtin_amdgcn_mfma_f32_16x16x32_bf16(al[i], bh, acc[i][j], 0, 0, 0);
                acc[i][j] = __builtin_amdgcn_mfma_f32_16x16x32_bf16(ah[i], bh, acc[i][j], 0, 0, 0);
            }
        }
    }

#pragma unroll
    for (int i = 0; i < 4; ++i) {
#pragma unroll
        for (int q = 0; q < 4; ++q) {
            const int m = m0 + (wr * 4 + i) * 16 + kg * 4 + q;
            int cm = m;
            if (crow) { cm = crow[m]; if (cm < 0) continue; }
            const float rs = rowscale ? rowscale[m] : 1.f;
#pragma unroll
            for (int j = 0; j < 4; ++j) {
                const int n = n0 + (wc * 4 + j) * 16 + lr;
                float v = acc[i][j][q];
                if (bias) v += bias[n];
                v *= rs;
                const size_t off = (size_t)cm * ldc + n;
                if (accumulate) v += C[off];
                if (add1) v += add1[off];
                if (add2) v += add2[off];
                C[off] = v;
            }
        }
    }
}

// ---------------------------------------------------------------- split-bf16 MFMA GEMM (f32-B fallback)
// Verbatim R3 kernel: used only if the workspace cannot hold weight planes.
__global__ __launch_bounds__(256)
void gemm_f_k(const float* __restrict__ A, int lda,
              const float* __restrict__ Bm, int ldb,
              float* __restrict__ C, int ldc, int K,
              const float* __restrict__ bias,
              const float* __restrict__ rowscale,
              const float* __restrict__ add1,
              const float* __restrict__ add2,
              int accumulate,
              const int* __restrict__ arow,
              const int* __restrict__ crow,
              const int* __restrict__ mlim)
{
    const int m0 = blockIdx.y * 128;
    if (mlim && m0 >= *mlim) return;

    __shared__ uint4 lds[2048];
    uint4* Ahi = lds;
    uint4* Alo = lds + 512;
    uint4* Bhi = lds + 1024;
    uint4* Blo = lds + 1536;

    const int t  = threadIdx.x;
    const int n0 = blockIdx.x * 128;

    const int sar = t >> 1;
    const int sak = (t & 1) << 4;
    const int sbc = t & 127;
    const int sbk = (t >> 7) << 4;
    int arow_eff = m0 + sar;
    if (arow) { const int r = arow[arow_eff]; arow_eff = (r < 0) ? 0 : r; }
    const float* Ap = A + (size_t)arow_eff * lda + sak;
    const float* Bp = Bm + (size_t)sbk * ldb + n0 + sbc;
    const int aslot = ((sar >> 4) * 4 + (sak >> 3)) * 16 + (sar & 15);
    const int bslot = ((sbc >> 4) * 4 + (sbk >> 3)) * 16 + (sbc & 15);

    const int w  = t >> 6, l = t & 63;
    const int wr = w >> 1, wc = w & 1;
    const int lr = l & 15, kg = l >> 4;

    floatx4 acc[4][4];
#pragma unroll
    for (int i = 0; i < 4; ++i)
#pragma unroll
        for (int j = 0; j < 4; ++j) acc[i][j] = (floatx4){0.f, 0.f, 0.f, 0.f};

    float af[16], bf[16];
    *(float4*)&af[0]  = *(const float4*)(Ap + 0);
    *(float4*)&af[4]  = *(const float4*)(Ap + 4);
    *(float4*)&af[8]  = *(const float4*)(Ap + 8);
    *(float4*)&af[12] = *(const float4*)(Ap + 12);
#pragma unroll
    for (int j = 0; j < 16; ++j) bf[j] = Bp[(size_t)j * ldb];

    for (int k0 = 0; k0 < K; k0 += 32) {
        __syncthreads();
        {
            uint4 h0, l0, h1, l1;
            split_pack8(&af[0], h0, l0);
            split_pack8(&af[8], h1, l1);
            Ahi[aslot] = h0; Ahi[aslot + 16] = h1;
            Alo[aslot] = l0; Alo[aslot + 16] = l1;
            split_pack8(&bf[0], h0, l0);
            split_pack8(&bf[8], h1, l1);
            Bhi[bslot] = h0; Bhi[bslot + 16] = h1;
            Blo[bslot] = l0; Blo[bslot + 16] = l1;
        }
        __syncthreads();

        if (k0 + 32 < K) {
            const int kn = k0 + 32;
            *(float4*)&af[0]  = *(const float4*)(Ap + kn + 0);
            *(float4*)&af[4]  = *(const float4*)(Ap + kn + 4);
            *(float4*)&af[8]  = *(const float4*)(Ap + kn + 8);
            *(float4*)&af[12] = *(const float4*)(Ap + kn + 12);
#pragma unroll
            for (int j = 0; j < 16; ++j) bf[j] = Bp[(size_t)(kn + j) * ldb];
        }

        bhalf8 ah[4], al[4];
#pragma unroll
        for (int i = 0; i < 4; ++i) {
            const int s = ((wr * 4 + i) * 4 + kg) * 16 + lr;
            ah[i] = as_b8(Ahi[s]);
            al[i] = as_b8(Alo[s]);
        }
#pragma unroll
        for (int j = 0; j < 4; ++j) {
            const int s = ((wc * 4 + j) * 4 + kg) * 16 + lr;
            const bhalf8 bh = as_b8(Bhi[s]);
            const bhalf8 bl = as_b8(Blo[s]);
#pragma unroll
            for (int i = 0; i < 4; ++i) {
                acc[i][j] = __builtin_amdgcn_mfma_f32_16x16x32_bf16(ah[i], bl, acc[i][j], 0, 0, 0);
                acc[i][j] = __builtin_amdgcn_mfma_f32_16x16x32_bf16(al[i], bh, acc[i][j], 0, 0, 0);
                acc[i][j] = __builtin_amdgcn_mfma_f32_16x16x32_bf16(ah[i], bh, acc[i][j], 0, 0, 0);
            }
        }
    }

#pragma unroll
    for (int i = 0; i < 4; ++i) {
#pragma unroll
        for (int q = 0; q < 4; ++q) {
            const int m = m0 + (wr * 4 + i) * 16 + kg * 4 + q;
            int cm = m;
            if (crow) { cm = crow[m]; if (cm < 0) continue; }
            const float rs = rowscale ? rowscale[m] : 1.f;
#pragma unroll
            for (int j = 0; j < 4; ++j) {
                const int n = n0 + (wc * 4 + j) * 16 + lr;
                float v = acc[i][j][q];
                if (bias) v += bias[n];
                v *= rs;
                const size_t off = (size_t)cm * ldc + n;
                if (accumulate) v += C[off];
                if (add1) v += add1[off];
                if (add2) v += add2[off];
                C[off] = v;
            }
        }
    }
}

// ---------------------------------------------------------------- RoPE (in place)
__global__ __launch_bounds__(256)
void rope_k(float* __restrict__ p, int nheads)
{
    const int idx = blockIdx.x * 256 + threadIdx.x;
    const int total = TT * nheads * (DH / 2);
    if (idx >= total) return;
    const int i  = idx & 63;
    const int hh = (idx >> 6) % nheads;
    const int tt = idx / (64 * nheads);
    const int s  = tt & (SS - 1);      // position within sequence (S pow2)
    const float freq = expf(-(float)i * (9.210340371976184f / 64.f)); // 10000^{-i/64}
    const float ang = (float)s * freq;
    float sn, cs;
    sincosf(ang, &sn, &cs);
    float* base = p + ((size_t)tt * nheads + hh) * DH;
    const float x1 = base[i], x2 = base[i + 64];
    base[i]      = x1 * cs - x2 * sn;
    base[i + 64] = x2 * cs + x1 * sn;
}

// ---------------------------------------------------------------- flash attention
// Grid (S/64, NQ, B); 256 threads. 64 queries x 32-key tiles, causal, GQA (kv = hq>>3).
static constexpr int QT   = 64;
static constexpr int KT   = 32;
static constexpr int QSTR = DH + 4;

__global__ __launch_bounds__(256)
void attn_k(const float* __restrict__ qb, const float* __restrict__ kb,
            const float* __restrict__ vb, float* __restrict__ ob)
{
    __shared__ float Qs[QT][QSTR];
    __shared__ float KVs[KT][QSTR];
    __shared__ float Ps[QT][KT + 1];
    __shared__ float Mrow[QT];
    __shared__ float Lrow[QT];

    const int t   = threadIdx.x;
    const int q0  = blockIdx.x * QT;
    const int hq  = blockIdx.y;
    const int bz  = blockIdx.z;
    const int kvh = hq >> 3;                    // NQ/NKV = 8
    const float scl = 0.08838834764831845f;     // 1/sqrt(128)

    for (int i4 = t; i4 < QT * (DH / 4); i4 += 256) {
        const int qi = i4 >> 5, c4 = i4 & 31;
        float4 v = *((const float4*)(qb + ((size_t)(bz * SS + q0 + qi) * NQ + hq) * DH) + c4);
        v.x *= scl; v.y *= scl; v.z *= scl; v.w *= scl;
        *(float4*)&Qs[qi][c4 << 2] = v;
    }
    if (t < QT) { Mrow[t] = -1e30f; Lrow[t] = 0.f; }

    const int tr = t >> 4;
    const int tc = t & 15;
    float O[4][8] = {};

    const int nk = q0 + QT;
    for (int k0 = 0; k0 < nk; k0 += KT) {
        float4 kreg[4], vreg[4];
#pragma unroll
        for (int i = 0; i < 4; ++i) {
            const int idx4 = t + (i << 8);
            const int kj = idx4 >> 5, c4 = idx4 & 31;
            const size_t roff = ((size_t)(bz * SS + k0 + kj) * NKV + kvh) * DH + (c4 << 2);
            kreg[i] = *(const float4*)(kb + roff);
            vreg[i] = *(const float4*)(vb + roff);
        }
        __syncthreads();
#pragma unroll
        for (int i = 0; i < 4; ++i) {
            const int idx4 = t + (i << 8);
            *(float4*)&KVs[idx4 >> 5][(idx4 & 31) << 2] = kreg[i];
        }
        __syncthreads();

        float s0[4] = {}, s1[4] = {};
#pragma unroll 8
        for (int d = 0; d < DH; d += 4) {
            const float4 ka = *(const float4*)&KVs[tc][d];
            const float4 kb4 = *(const float4*)&KVs[tc + 16][d];
#pragma unroll
            for (int i = 0; i < 4; ++i) {
                const float4 qv = *(const float4*)&Qs[(tr << 2) + i][d];
                s0[i] += qv.x * ka.x + qv.y * ka.y + qv.z * ka.z + qv.w * ka.w;
                s1[i] += qv.x * kb4.x + qv.y * kb4.y + qv.z * kb4.z + qv.w * kb4.w;
            }
        }

#pragma unroll
        for (int i = 0; i < 4; ++i) {
            const int qg = q0 + (tr << 2) + i;
            const float a  = (k0 + tc      <= qg) ? s0[i] : -1e30f;
            const float bq_ = (k0 + tc + 16 <= qg) ? s1[i] : -1e30f;
            float mt = fmaxf(a, bq_);
#pragma unroll
            for (int o = 1; o < 16; o <<= 1) mt = fmaxf(mt, __shfl_xor(mt, o, 64));
            const float mold = Mrow[(tr << 2) + i];
            const float mnew = fmaxf(mold, mt);
            const float alpha = __expf(mold - mnew);
            const float p0 = __expf(a - mnew);
            const float p1 = __expf(bq_ - mnew);
            float ls = p0 + p1;
#pragma unroll
            for (int o = 1; o < 16; o <<= 1) ls += __shfl_xor(ls, o, 64);
            if (tc == 0) {
                Mrow[(tr << 2) + i] = mnew;
                Lrow[(tr << 2) + i] = alpha * Lrow[(tr << 2) + i] + ls;
            }
            Ps[(tr << 2) + i][tc]      = p0;
            Ps[(tr << 2) + i][tc + 16] = p1;
#pragma unroll
            for (int j = 0; j < 8; ++j) O[i][j] *= alpha;
        }
        __syncthreads();
#pragma unroll
        for (int i = 0; i < 4; ++i) {
            const int idx4 = t + (i << 8);
            *(float4*)&KVs[idx4 >> 5][(idx4 & 31) << 2] = vreg[i];
        }
        __syncthreads();

#pragma unroll 4
        for (int kj = 0; kj < KT; ++kj) {
            const float4 v0 = *(const float4*)&KVs[kj][tc << 2];
            const float4 v1 = *(const float4*)&KVs[kj][64 + (tc << 2)];
#pragma unroll
            for (int i = 0; i < 4; ++i) {
                const float p = Ps[(tr << 2) + i][kj];
                O[i][0] += p * v0.x; O[i][1] += p * v0.y;
                O[i][2] += p * v0.z; O[i][3] += p * v0.w;
                O[i][4] += p * v1.x; O[i][5] += p * v1.y;
                O[i][6] += p * v1.z; O[i][7] += p * v1.w;
            }
        }
    }

#pragma unroll
    for (int i = 0; i < 4; ++i) {
        const int qi = (tr << 2) + i;
        const float inv = 1.f / Lrow[qi];
        float* base = ob + ((size_t)(bz * SS + q0 + qi) * NQ + hq) * DH;
        float4 o0, o1;
        o0.x = O[i][0] * inv; o0.y = O[i][1] * inv; o0.z = O[i][2] * inv; o0.w = O[i][3] * inv;
        o1.x = O[i][4] * inv; o1.y = O[i][5] * inv; o1.z = O[i][6] * inv; o1.w = O[i][7] * inv;
        *(float4*)(base + (tc << 2)) = o0;
        *(float4*)(base + 64 + (tc << 2)) = o1;
    }
}

// ---------------------------------------------------------------- router (+ shared sigmoid gate)
__global__ __launch_bounds__(256)
void router_k(const float* __restrict__ tb, const float* __restrict__ rw,
              const float* __restrict__ sgw, float* __restrict__ dw,
              float* __restrict__ gs)
{
    const int tok = blockIdx.x;
    const float* xr = tb + (size_t)tok * HH;
    float acc[EE] = {};
    float ag = 0.f;
    for (int h = threadIdx.x; h < HH; h += 256) {
        const float xv = xr[h];
        const float4 r0 = *(const float4*)(rw + (size_t)h * EE);
        const float4 r1 = *(const float4*)(rw + (size_t)h * EE + 4);
        acc[0] += xv * r0.x; acc[1] += xv * r0.y; acc[2] += xv * r0.z; acc[3] += xv * r0.w;
        acc[4] += xv * r1.x; acc[5] += xv * r1.y; acc[6] += xv * r1.z; acc[7] += xv * r1.w;
        ag += xv * sgw[h];
    }
#pragma unroll
    for (int e = 0; e < EE; ++e)
#pragma unroll
        for (int o = 32; o > 0; o >>= 1) acc[e] += __shfl_down(acc[e], o, 64);
#pragma unroll
    for (int o = 32; o > 0; o >>= 1) ag += __shfl_down(ag, o, 64);
    __shared__ float red[4][EE + 1];
    if ((threadIdx.x & 63) == 0) {
        const int w = threadIdx.x >> 6;
#pragma unroll
        for (int e = 0; e < EE; ++e) red[w][e] = acc[e];
        red[w][EE] = ag;
    }
    __syncthreads();
    if (threadIdx.x == 0) {
        float l[EE];
#pragma unroll
        for (int e = 0; e < EE; ++e) l[e] = red[0][e] + red[1][e] + red[2][e] + red[3][e];
        const float g = red[0][EE] + red[1][EE] + red[2][EE] + red[3][EE];
        gs[tok] = 1.f / (1.f + expf(-g));
        float m = l[0];
        for (int e = 1; e < EE; ++e) m = fmaxf(m, l[e]);
        float p[EE]; float sum = 0.f;
        for (int e = 0; e < EE; ++e) { p[e] = expf(l[e] - m); sum += p[e]; }
        for (int e = 0; e < EE; ++e) p[e] /= sum;
        bool used[EE] = {};
        float wsum = 0.f;
        for (int k = 0; k < KSEL; ++k) {       // top-4, ties -> lowest index (lax.top_k)
            int bi = 0; float bv = -1.f;
            for (int e = 0; e < EE; ++e)
                if (!used[e] && p[e] > bv) { bv = p[e]; bi = e; }
            used[bi] = true; wsum += bv;
        }
        for (int e = 0; e < EE; ++e)
            dw[(size_t)tok * EE + e] = used[e] ? p[e] / wsum : 0.f;
    }
}

// ---------------------------------------------------------------- sparse-MoE routing lists
__global__ void route_init_k(int* __restrict__ cnt)
{
    if (threadIdx.x < EE) cnt[threadIdx.x] = 0;
}

__global__ __launch_bounds__(256)
void route_fill_k(const float* __restrict__ dw, int* __restrict__ cnt,
                  int* __restrict__ tokidx, float* __restrict__ tokw)
{
    const int t = blockIdx.x * 256 + threadIdx.x;
    if (t >= TT) return;
#pragma unroll
    for (int e = 0; e < EE; ++e) {
        const float w = dw[(size_t)t * EE + e];
        if (w > 0.f) {
            const int pos = atomicAdd(cnt + e, 1);
            tokidx[e * TT + pos] = t;
            tokw[e * TT + pos]   = w;
        }
    }
}

// pad each expert's list to a multiple of 128 (GEMM M-tile) with -1 sentinels
__global__ void route_pad_k(const int* __restrict__ cnt, int* __restrict__ mpad,
                            int* __restrict__ tokidx)
{
    const int e = blockIdx.x;
    const int c = cnt[e];
    const int mp = (c + 127) & ~127;
    if (threadIdx.x == 0) mpad[e] = mp;
    for (int i = c + threadIdx.x; i < mp; i += 64) tokidx[e * TT + i] = -1;
}

// ---------------------------------------------------------------- silu(g)*u (*dw[token,e]), optional row limit
__global__ __launch_bounds__(256)
void silu_mul_k(float* __restrict__ g, const float* __restrict__ u,
                const float* __restrict__ dw, int ecol, int icols, int n,
                const int* __restrict__ mlim)
{
    const int idx = blockIdx.x * 256 + threadIdx.x;
    if (idx >= n) return;
    if (mlim && idx >= (*mlim) * icols) return;
    const float gv = g[idx];
    const float uv = u[idx];
    float v = gv / (1.f + __expf(-gv)) * uv;
    if (dw) v *= dw[(size_t)(idx / icols) * EE + ecol];
    g[idx] = v;
}

// ---------------------------------------------------------------- launcher
extern "C" void kernel_launch(void* const* d_in, const int* in_sizes, int n_in,
                              void* d_out, int out_size, void* d_ws, size_t ws_size,
                              hipStream_t stream)
{
    (void)in_sizes; (void)n_in; (void)out_size;
    const float* x   = (const float*)d_in[0];
    const float* ln1 = (const float*)d_in[1];
    const float* wq  = (const float*)d_in[2];
    const float* bq  = (const float*)d_in[3];
    const float* wk  = (const float*)d_in[4];
    const float* bk  = (const float*)d_in[5];
    const float* wv  = (const float*)d_in[6];
    const float* bv  = (const float*)d_in[7];
    const float* wo  = (const float*)d_in[8];
    const float* ln2 = (const float*)d_in[9];
    const float* rww = (const float*)d_in[10];
    const float* wg  = (const float*)d_in[11];
    const float* wu  = (const float*)d_in[12];
    const float* wd  = (const float*)d_in[13];
    const float* swg = (const float*)d_in[14];
    const float* swu = (const float*)d_in[15];
    const float* swd = (const float*)d_in[16];
    const float* sgw = (const float*)d_in[17];
    float* out = (float*)d_out;

    // f32 workspace region (same as R3); attnb aliases hbuf, tb aliases qb
    float* ws   = (float*)d_ws;
    float* hbuf = ws;
    float* qb   = hbuf + (size_t)TT * HH;
    float* kb   = qb   + (size_t)TT * NQ * DH;
    float* vb   = kb   + (size_t)TT * NKV * DH;
    float* x1   = vb   + (size_t)TT * NKV * DH;
    float* moe  = x1   + (size_t)TT * HH;
    float* gbuf = moe  + (size_t)TT * HH;
    float* ubuf = gbuf + (size_t)TT * IMOE;
    float* dw   = ubuf + (size_t)TT * IMOE;
    float* gs   = dw   + (size_t)TT * EE;
    int*   tokidx = (int*)(gs + TT);                 // [EE][TT]
    float* tokw   = (float*)(tokidx + (size_t)EE * TT); // [EE][TT]
    int*   cnt    = (int*)(tokw + (size_t)EE * TT);  // [EE]
    int*   mpad   = cnt + EE;                        // [EE]
    const size_t need_f32 = (size_t)((char*)(mpad + EE) - (char*)ws);
    if (ws_size < need_f32) return;                  // workspace too small

    // bf16 hi/lo weight planes (transposed [N][K]); 16B-aligned
    char* pc0 = (char*)(mpad + EE);
    pc0 = (char*)(((uintptr_t)pc0 + 15) & ~(uintptr_t)15);
    unsigned short* p = (unsigned short*)pc0;
    unsigned short* wq_th = p; p += (size_t)HH * (NQ * DH);
    unsigned short* wq_tl = p; p += (size_t)HH * (NQ * DH);
    unsigned short* wk_th = p; p += (size_t)HH * (NKV * DH);
    unsigned short* wk_tl = p; p += (size_t)HH * (NKV * DH);
    unsigned short* wv_th = p; p += (size_t)HH * (NKV * DH);
    unsigned short* wv_tl = p; p += (size_t)HH * (NKV * DH);
    unsigned short* wo_th = p; p += (size_t)HH * HH;
    unsigned short* wo_tl = p; p += (size_t)HH * HH;
    unsigned short* wg_th = p; p += (size_t)EE * HH * IMOE;
    unsigned short* wg_tl = p; p += (size_t)EE * HH * IMOE;
    unsigned short* wu_th = p; p += (size_t)EE * HH * IMOE;
    unsigned short* wu_tl = p; p += (size_t)EE * HH * IMOE;
    unsigned short* wd_th = p; p += (size_t)EE * IMOE * HH;
    unsigned short* wd_tl = p; p += (size_t)EE * IMOE * HH;
    unsigned short* sg_th = p; p += (size_t)HH * ISH;
    unsigned short* sg_tl = p; p += (size_t)HH * ISH;
    unsigned short* su_th = p; p += (size_t)HH * ISH;
    unsigned short* su_tl = p; p += (size_t)HH * ISH;
    unsigned short* sd_th = p; p += (size_t)ISH * HH;
    unsigned short* sd_tl = p; p += (size_t)ISH * HH;
    const size_t need_planes = (size_t)((char*)p - (char*)ws);
    const bool planes = (ws_size >= need_planes);

    float* attnb = hbuf;   // hbuf dead after q/k/v projections
    float* tb    = qb;     // qb dead after attention

    // 0) weight conversion (independent of activations; front-loaded)
    if (planes) {
        splitw_k<<<dim3((NQ * DH) / 64, HH / 64), 256, 0, stream>>>(wq, HH, NQ * DH, wq_th, wq_tl);
        splitw_k<<<dim3((NKV * DH) / 64, HH / 64), 256, 0, stream>>>(wk, HH, NKV * DH, wk_th, wk_tl);
        splitw_k<<<dim3((NKV * DH) / 64, HH / 64), 256, 0, stream>>>(wv, HH, NKV * DH, wv_th, wv_tl);
        splitw_k<<<dim3(HH / 64, HH / 64), 256, 0, stream>>>(wo, NQ * DH, HH, wo_th, wo_tl);
        splitw_k<<<dim3(IMOE / 64, HH / 64, EE), 256, 0, stream>>>(wg, HH, IMOE, wg_th, wg_tl);
        splitw_k<<<dim3(IMOE / 64, HH / 64, EE), 256, 0, stream>>>(wu, HH, IMOE, wu_th, wu_tl);
        splitw_k<<<dim3(HH / 64, IMOE / 64, EE), 256, 0, stream>>>(wd, IMOE, HH, wd_th, wd_tl);
        splitw_k<<<dim3(ISH / 64, HH / 64), 256, 0, stream>>>(swg, HH, ISH, sg_th, sg_tl);
        splitw_k<<<dim3(ISH / 64, HH / 64), 256, 0, stream>>>(swu, HH, ISH, su_th, su_tl);
        splitw_k<<<dim3(HH / 64, ISH / 64), 256, 0, stream>>>(swd, ISH, HH, sd_th, sd_tl);
    }

    // 1) pre-norm
    rmsnorm_k<<<TT, 256, 0, stream>>>(x, ln1, hbuf);
    // 2) q/k/v projections (+bias)
    if (planes) {
        gemm_p_k<<<dim3((NQ * DH) / 128, TT / 128), 256, 0, stream>>>(hbuf, HH, wq_th, wq_tl, HH, qb, NQ * DH, HH, bq, nullptr, nullptr, nullptr, 0, nullptr, nullptr, nullptr);
        gemm_p_k<<<dim3((NKV * DH) / 128, TT / 128), 256, 0, stream>>>(hbuf, HH, wk_th, wk_tl, HH, kb, NKV * DH, HH, bk, nullptr, nullptr, nullptr, 0, nullptr, nullptr, nullptr);
        gemm_p_k<<<dim3((NKV * DH) / 128, TT / 128), 256, 0, stream>>>(hbuf, HH, wv_th, wv_tl, HH, vb, NKV * DH, HH, bv, nullptr, nullptr, nullptr, 0, nullptr, nullptr, nullptr);
    } else {
        gemm_f_k<<<dim3((NQ * DH) / 128, TT / 128), 256, 0, stream>>>(hbuf, HH, wq, NQ * DH, qb, NQ * DH, HH, bq, nullptr, nullptr, nullptr, 0, nullptr, nullptr, nullptr);
        gemm_f_k<<<dim3((NKV * DH) / 128, TT / 128), 256, 0, stream>>>(hbuf, HH, wk, NKV * DH, kb, NKV * DH, HH, bk, nullptr, nullptr, nullptr, 0, nullptr, nullptr, nullptr);
        gemm_f_k<<<dim3((NKV * DH) / 128, TT / 128), 256, 0, stream>>>(hbuf, HH, wv, NKV * DH, vb, NKV * DH, HH, bv, nullptr, nullptr, nullptr, 0, nullptr, nullptr, nullptr);
    }
    // 3) RoPE
    rope_k<<<(TT * NQ * 64 + 255) / 256, 256, 0, stream>>>(qb, NQ);
    rope_k<<<(TT * NKV * 64 + 255) / 256, 256, 0, stream>>>(kb, NKV);
    // 4) causal GQA attention
    attn_k<<<dim3(SS / QT, NQ, BB), 256, 0, stream>>>(qb, kb, vb, attnb);
    // 5) output projection + residual
    if (planes)
        gemm_p_k<<<dim3(HH / 128, TT / 128), 256, 0, stream>>>(attnb, NQ * DH, wo_th, wo_tl, NQ * DH, x1, HH, NQ * DH, nullptr, nullptr, x, nullptr, 0, nullptr, nullptr, nullptr);
    else
        gemm_f_k<<<dim3(HH / 128, TT / 128), 256, 0, stream>>>(attnb, NQ * DH, wo, HH, x1, HH, NQ * DH, nullptr, nullptr, x, nullptr, 0, nullptr, nullptr, nullptr);
    // 6) post-attn norm + router (+ shared sigmoid gate)
    rmsnorm_k<<<TT, 256, 0, stream>>>(x1, ln2, tb);
    router_k<<<TT, 256, 0, stream>>>(tb, rww, sgw, dw, gs);
    // 6b) sparse routing lists + zero the MoE accumulator
    zero_k<<<(TT * HH / 4 + 255) / 256, 256, 0, stream>>>(moe, TT * HH / 4);
    route_init_k<<<1, 64, 0, stream>>>(cnt);
    route_fill_k<<<(TT + 255) / 256, 256, 0, stream>>>(dw, cnt, tokidx, tokw);
    route_pad_k<<<EE, 64, 0, stream>>>(cnt, mpad, tokidx);
    // 7) experts — SPARSE: only tokens routed to expert e
    const int nmoe = TT * IMOE;
    for (int e = 0; e < EE; ++e) {
        const int*   idx = tokidx + e * TT;
        const float* twe = tokw + e * TT;
        const int*   ml  = mpad + e;
        if (planes) {
            gemm_p_k<<<dim3(IMOE / 128, TT / 128), 256, 0, stream>>>(tb, HH, wg_th + (size_t)e * HH * IMOE, wg_tl + (size_t)e * HH * IMOE, HH, gbuf, IMOE, HH, nullptr, nullptr, nullptr, nullptr, 0, idx, nullptr, ml);
            gemm_p_k<<<dim3(IMOE / 128, TT / 128), 256, 0, stream>>>(tb, HH, wu_th + (size_t)e * HH * IMOE, wu_tl + (size_t)e * HH * IMOE, HH, ubuf, IMOE, HH, nullptr, nullptr, nullptr, nullptr, 0, idx, nullptr, ml);
            silu_mul_k<<<(nmoe + 255) / 256, 256, 0, stream>>>(gbuf, ubuf, nullptr, 0, IMOE, nmoe, ml);
            gemm_p_k<<<dim3(HH / 128, TT / 128), 256, 0, stream>>>(gbuf, IMOE, wd_th + (size_t)e * IMOE * HH, wd_tl + (size_t)e * IMOE * HH, IMOE, moe, HH, IMOE, nullptr, twe, nullptr, nullptr, 1, nullptr, idx, ml);
        } else {
            const float* wge = wg + (size_t)e * HH * IMOE;
            const float* wue = wu + (size_t)e * HH * IMOE;
            const float* wde = wd + (size_t)e * IMOE * HH;
            gemm_f_k<<<dim3(IMOE / 128, TT / 128), 256, 0, stream>>>(tb, HH, wge, IMOE, gbuf, IMOE, HH, nullptr, nullptr, nullptr, nullptr, 0, idx, nullptr, ml);
            gemm_f_k<<<dim3(IMOE / 128, TT / 128), 256, 0, stream>>>(tb, HH, wue, IMOE, ubuf, IMOE, HH, nullptr, nullptr, nullptr, nullptr, 0, idx, nullptr, ml);
            silu_mul_k<<<(nmoe + 255) / 256, 256, 0, stream>>>(gbuf, ubuf, nullptr, 0, IMOE, nmoe, ml);
            gemm_f_k<<<dim3(HH / 128, TT / 128), 256, 0, stream>>>(gbuf, IMOE, wde, HH, moe, HH, IMOE, nullptr, twe, nullptr, nullptr, 1, nullptr, idx, ml);
        }
    }
    // 8) shared expert, chunked over I_SH in 4 x 1408; last chunk fuses final residual sum
    for (int c = 0; c < 4; ++c) {
        if (planes) {
            gemm_p_k<<<dim3(IMOE / 128, TT / 128), 256, 0, stream>>>(tb, HH, sg_th + (size_t)c * IMOE * HH, sg_tl + (size_t)c * IMOE * HH, HH, gbuf, IMOE, HH, nullptr, nullptr, nullptr, nullptr, 0, nullptr, nullptr, nullptr);
            gemm_p_k<<<dim3(IMOE / 128, TT / 128), 256, 0, stream>>>(tb, HH, su_th + (size_t)c * IMOE * HH, su_tl + (size_t)c * IMOE * HH, HH, ubuf, IMOE, HH, nullptr, nullptr, nullptr, nullptr, 0, nullptr, nullptr, nullptr);
            silu_mul_k<<<(nmoe + 255) / 256, 256, 0, stream>>>(gbuf, ubuf, nullptr, 0, IMOE, nmoe, nullptr);
            if (c < 3)
                gemm_p_k<<<dim3(HH / 128, TT / 128), 256, 0, stream>>>(gbuf, IMOE, sd_th + (size_t)c * IMOE, sd_tl + (size_t)c * IMOE, ISH, moe, HH, IMOE, nullptr, gs, nullptr, nullptr, 1, nullptr, nullptr, nullptr);
            else  // out = x1 + moe + gs .* (hs_c @ swdown_c)
                gemm_p_k<<<dim3(HH / 128, TT / 128), 256, 0, stream>>>(gbuf, IMOE, sd_th + (size_t)c * IMOE, sd_tl + (size_t)c * IMOE, ISH, out, HH, IMOE, nullptr, gs, moe, x1, 0, nullptr, nullptr, nullptr);
        } else {
            const float* swgc = swg + (size_t)c * IMOE;
            const float* swuc = swu + (size_t)c * IMOE;
            const float* swdc = swd + (size_t)c * IMOE * HH;
            gemm_f_k<<<dim3(IMOE / 128, TT / 128), 256, 0, stream>>>(tb, HH, swgc, ISH, gbuf, IMOE, HH, nullptr, nullptr, nullptr, nullptr, 0, nullptr, nullptr, nullptr);
            gemm_f_k<<<dim3(IMOE / 128, TT / 128), 256, 0, stream>>>(tb, HH, swuc, ISH, ubuf, IMOE, HH, nullptr, nullptr, nullptr, nullptr, 0, nullptr, nullptr, nullptr);
            silu_mul_k<<<(nmoe + 255) / 256, 256, 0, stream>>>(gbuf, ubuf, nullptr, 0, IMOE, nmoe, nullptr);
            if (c < 3)
                gemm_f_k<<<dim3(HH / 128, TT / 128), 256, 0, stream>>>(gbuf, IMOE, swdc, HH, moe, HH, IMOE, nullptr, gs, nullptr, nullptr, 1, nullptr, nullptr, nullptr);
            else
                gemm_f_k<<<dim3(HH / 128, TT / 128), 256, 0, stream>>>(gbuf, IMOE, swdc, HH, out, HH, IMOE, nullptr, gs, moe, x1, 0, nullptr, nullptr, nullptr);
        }
    }
}

// Round 5
// 4861.141 us; speedup vs baseline: 2.6169x; 1.2148x over previous
//
#include <hip/hip_runtime.h>
#include <math.h>

// Problem constants (QwenMoeTransformerDecoder: B=2,S=2048,H=2048,E=8,K=4)
static constexpr int BB   = 2;
static constexpr int SS   = 2048;
static constexpr int HH   = 2048;
static constexpr int TT   = BB * SS;   // 4096 tokens
static constexpr int EE   = 8;
static constexpr int KSEL = 4;
static constexpr int IMOE = 1408;
static constexpr int ISH  = 5632;      // = 4 * IMOE (chunked)
static constexpr int NQ   = 16;
static constexpr int NKV  = 2;
static constexpr int DH   = 128;

typedef __attribute__((ext_vector_type(8))) short bhalf8;
typedef __attribute__((ext_vector_type(4))) float floatx4;

union U16B { uint4 u; bhalf8 s; };
__device__ __forceinline__ bhalf8 as_b8(uint4 u) { U16B x; x.u = u; return x.s; }

// split 8 consecutive f32 into hi/lo bf16 planes (truncation split: exact residual)
__device__ __forceinline__ void split_pack8(const float* f, uint4& hi, uint4& lo)
{
    unsigned h[4], lw[4];
#pragma unroll
    for (int q = 0; q < 4; ++q) {
        const float f0 = f[2 * q], f1 = f[2 * q + 1];
        const unsigned u0 = __float_as_uint(f0), u1 = __float_as_uint(f1);
        const unsigned m0 = u0 & 0xffff0000u, m1 = u1 & 0xffff0000u;
        h[q] = (u0 >> 16) | m1;
        const float l0 = f0 - __uint_as_float(m0);   // exact
        const float l1 = f1 - __uint_as_float(m1);   // exact
        lw[q] = (__float_as_uint(l0) >> 16) | (__float_as_uint(l1) & 0xffff0000u);
    }
    hi = make_uint4(h[0], h[1], h[2], h[3]);
    lo = make_uint4(lw[0], lw[1], lw[2], lw[3]);
}

// ---------------------------------------------------------------- RMSNorm
__global__ __launch_bounds__(256)
void rmsnorm_k(const float* __restrict__ x, const float* __restrict__ sc,
               float* __restrict__ o)
{
    const int row = blockIdx.x;
    const float4* xr = (const float4*)(x + (size_t)row * HH);
    const float4* sr = (const float4*)sc;
    float4* orow = (float4*)(o + (size_t)row * HH);
    float ss = 0.f;
    for (int i = threadIdx.x; i < HH / 4; i += 256) {
        float4 v = xr[i];
        ss += v.x * v.x + v.y * v.y + v.z * v.z + v.w * v.w;
    }
#pragma unroll
    for (int off = 32; off > 0; off >>= 1) ss += __shfl_down(ss, off, 64);
    __shared__ float red[4];
    if ((threadIdx.x & 63) == 0) red[threadIdx.x >> 6] = ss;
    __syncthreads();
    const float tot = red[0] + red[1] + red[2] + red[3];
    const float inv = rsqrtf(tot / (float)HH + 1e-5f);
    for (int i = threadIdx.x; i < HH / 4; i += 256) {
        float4 v = xr[i]; float4 s = sr[i];
        float4 w;
        w.x = v.x * inv * s.x; w.y = v.y * inv * s.y;
        w.z = v.z * inv * s.z; w.w = v.w * inv * s.w;
        orow[i] = w;
    }
}

// ---------------------------------------------------------------- zero fill (float4 granularity)
__global__ __launch_bounds__(256)
void zero_k(float* __restrict__ p, int n4)
{
    const int i = blockIdx.x * 256 + threadIdx.x;
    if (i < n4) ((float4*)p)[i] = make_float4(0.f, 0.f, 0.f, 0.f);
}

// ---------------------------------------------------------------- weight transpose+split
// W f32 [K][N] row-major  ->  th/tl bf16 planes [N][K] (truncation split).
__global__ __launch_bounds__(256)
void splitw_k(const float* __restrict__ W, int K, int N,
              unsigned short* __restrict__ th, unsigned short* __restrict__ tl)
{
    const size_t zoff = (size_t)blockIdx.z * K * N;
    W += zoff; th += zoff; tl += zoff;
    __shared__ float tile[64][65];
    const int k0 = blockIdx.y * 64;
    const int n0 = blockIdx.x * 64;
    const int t  = threadIdx.x;
    const int c  = t & 63, rq = t >> 6;
#pragma unroll
    for (int r = 0; r < 16; ++r) {
        const int kk = r * 4 + rq;
        tile[kk][c] = W[(size_t)(k0 + kk) * N + n0 + c];
    }
    __syncthreads();
#pragma unroll
    for (int r = 0; r < 16; ++r) {
        const int nn = r * 4 + rq;
        const float v = tile[c][nn];                  // = W[k0+c][n0+nn]
        const unsigned u  = __float_as_uint(v);
        const unsigned hm = u & 0xffff0000u;
        const float lo = v - __uint_as_float(hm);     // exact
        th[(size_t)(n0 + nn) * K + k0 + c] = (unsigned short)(u >> 16);
        tl[(size_t)(n0 + nn) * K + k0 + c] = (unsigned short)(__float_as_uint(lo) >> 16);
    }
}

// ---------------------------------------------------------------- split-bf16 MFMA GEMM (plane-B)
__global__ __launch_bounds__(256)
void gemm_p_k(const float* __restrict__ A, int lda,
              const unsigned short* __restrict__ Bth,
              const unsigned short* __restrict__ Btl, int ldbt,
              float* __restrict__ C, int ldc, int K,
              const float* __restrict__ bias,
              const float* __restrict__ rowscale,
              const float* __restrict__ add1,
              const float* __restrict__ add2,
              int accumulate,
              const int* __restrict__ arow,
              const int* __restrict__ crow,
              const int* __restrict__ mlim)
{
    const int m0 = blockIdx.y * 128;
    if (mlim && m0 >= *mlim) return;       // uniform exit, before any barrier

    __shared__ uint4 lds[2048];            // Ahi[512] Alo[512] Bhi[512] Blo[512] = 32KB
    uint4* Ahi = lds;
    uint4* Alo = lds + 512;
    uint4* Bhi = lds + 1024;
    uint4* Blo = lds + 1536;

    const int t  = threadIdx.x;
    const int n0 = blockIdx.x * 128;

    const int sar = t >> 1;            // 0..127  A tile row
    const int sak = (t & 1) << 4;      // 0/16    A k-offset
    const int sbc = t & 127;           // 0..127  B tile col
    const int sbk = (t >> 7) << 4;     // 0/16    B k-offset
    int arow_eff = m0 + sar;
    if (arow) { const int r = arow[arow_eff]; arow_eff = (r < 0) ? 0 : r; }
    const float* Ap = A + (size_t)arow_eff * lda + sak;
    const unsigned short* Bph = Bth + (size_t)(n0 + sbc) * ldbt + sbk;
    const unsigned short* Bpl = Btl + (size_t)(n0 + sbc) * ldbt + sbk;
    const int aslot = ((sar >> 4) * 4 + (sak >> 3)) * 16 + (sar & 15);
    const int bslot = ((sbc >> 4) * 4 + (sbk >> 3)) * 16 + (sbc & 15);

    const int w  = t >> 6, l = t & 63;
    const int wr = w >> 1, wc = w & 1;     // 2x2 waves, each 64x64
    const int lr = l & 15, kg = l >> 4;    // frag lane coords

    floatx4 acc[4][4];
#pragma unroll
    for (int i = 0; i < 4; ++i)
#pragma unroll
        for (int j = 0; j < 4; ++j) acc[i][j] = (floatx4){0.f, 0.f, 0.f, 0.f};

    float af[16];
    uint4 rbh0, rbh1, rbl0, rbl1;
    *(float4*)&af[0]  = *(const float4*)(Ap + 0);
    *(float4*)&af[4]  = *(const float4*)(Ap + 4);
    *(float4*)&af[8]  = *(const float4*)(Ap + 8);
    *(float4*)&af[12] = *(const float4*)(Ap + 12);
    rbh0 = *(const uint4*)(Bph);
    rbh1 = *(const uint4*)(Bph + 8);
    rbl0 = *(const uint4*)(Bpl);
    rbl1 = *(const uint4*)(Bpl + 8);

    for (int k0 = 0; k0 < K; k0 += 32) {
        __syncthreads();                   // previous frag reads done
        {
            uint4 h0, l0, h1, l1;
            split_pack8(&af[0], h0, l0);
            split_pack8(&af[8], h1, l1);
            Ahi[aslot] = h0; Ahi[aslot + 16] = h1;
            Alo[aslot] = l0; Alo[aslot + 16] = l1;
            Bhi[bslot] = rbh0; Bhi[bslot + 16] = rbh1;
            Blo[bslot] = rbl0; Blo[bslot + 16] = rbl1;
        }
        __syncthreads();                   // tile ready

        if (k0 + 32 < K) {                 // prefetch next tile (overlaps MFMA phase)
            const int kn = k0 + 32;
            *(float4*)&af[0]  = *(const float4*)(Ap + kn + 0);
            *(float4*)&af[4]  = *(const float4*)(Ap + kn + 4);
            *(float4*)&af[8]  = *(const float4*)(Ap + kn + 8);
            *(float4*)&af[12] = *(const float4*)(Ap + kn + 12);
            rbh0 = *(const uint4*)(Bph + kn);
            rbh1 = *(const uint4*)(Bph + kn + 8);
            rbl0 = *(const uint4*)(Bpl + kn);
            rbl1 = *(const uint4*)(Bpl + kn + 8);
        }

        bhalf8 ah[4], al[4];
#pragma unroll
        for (int i = 0; i < 4; ++i) {
            const int s = ((wr * 4 + i) * 4 + kg) * 16 + lr;
            ah[i] = as_b8(Ahi[s]);
            al[i] = as_b8(Alo[s]);
        }
#pragma unroll
        for (int j = 0; j < 4; ++j) {
            const int s = ((wc * 4 + j) * 4 + kg) * 16 + lr;
            const bhalf8 bh = as_b8(Bhi[s]);
            const bhalf8 bl = as_b8(Blo[s]);
#pragma unroll
            for (int i = 0; i < 4; ++i) {
                acc[i][j] = __builtin_amdgcn_mfma_f32_16x16x32_bf16(ah[i], bl, acc[i][j], 0, 0, 0);
                acc[i][j] = __builtin_amdgcn_mfma_f32_16x16x32_bf16(al[i], bh, acc[i][j], 0, 0, 0);
                acc[i][j] = __builtin_amdgcn_mfma_f32_16x16x32_bf16(ah[i], bh, acc[i][j], 0, 0, 0);
            }
        }
    }

#pragma unroll
    for (int i = 0; i < 4; ++i) {
#pragma unroll
        for (int q = 0; q < 4; ++q) {
            const int m = m0 + (wr * 4 + i) * 16 + kg * 4 + q;
            int cm = m;
            if (crow) { cm = crow[m]; if (cm < 0) continue; }
            const float rs = rowscale ? rowscale[m] : 1.f;
#pragma unroll
            for (int j = 0; j < 4; ++j) {
                const int n = n0 + (wc * 4 + j) * 16 + lr;
                float v = acc[i][j][q];
                if (bias) v += bias[n];
                v *= rs;
                const size_t off = (size_t)cm * ldc + n;
                if (accumulate) v += C[off];
                if (add1) v += add1[off];
                if (add2) v += add2[off];
                C[off] = v;
            }
        }
    }
}

// ---------------------------------------------------------------- split-bf16 MFMA GEMM (f32-B fallback)
__global__ __launch_bounds__(256)
void gemm_f_k(const float* __restrict__ A, int lda,
              const float* __restrict__ Bm, int ldb,
              float* __restrict__ C, int ldc, int K,
              const float* __restrict__ bias,
              const float* __restrict__ rowscale,
              const float* __restrict__ add1,
              const float* __restrict__ add2,
              int accumulate,
              const int* __restrict__ arow,
              const int* __restrict__ crow,
              const int* __restrict__ mlim)
{
    const int m0 = blockIdx.y * 128;
    if (mlim && m0 >= *mlim) return;

    __shared__ uint4 lds[2048];
    uint4* Ahi = lds;
    uint4* Alo = lds + 512;
    uint4* Bhi = lds + 1024;
    uint4* Blo = lds + 1536;

    const int t  = threadIdx.x;
    const int n0 = blockIdx.x * 128;

    const int sar = t >> 1;
    const int sak = (t & 1) << 4;
    const int sbc = t & 127;
    const int sbk = (t >> 7) << 4;
    int arow_eff = m0 + sar;
    if (arow) { const int r = arow[arow_eff]; arow_eff = (r < 0) ? 0 : r; }
    const float* Ap = A + (size_t)arow_eff * lda + sak;
    const float* Bp = Bm + (size_t)sbk * ldb + n0 + sbc;
    const int aslot = ((sar >> 4) * 4 + (sak >> 3)) * 16 + (sar & 15);
    const int bslot = ((sbc >> 4) * 4 + (sbk >> 3)) * 16 + (sbc & 15);

    const int w  = t >> 6, l = t & 63;
    const int wr = w >> 1, wc = w & 1;
    const int lr = l & 15, kg = l >> 4;

    floatx4 acc[4][4];
#pragma unroll
    for (int i = 0; i < 4; ++i)
#pragma unroll
        for (int j = 0; j < 4; ++j) acc[i][j] = (floatx4){0.f, 0.f, 0.f, 0.f};

    float af[16], bf[16];
    *(float4*)&af[0]  = *(const float4*)(Ap + 0);
    *(float4*)&af[4]  = *(const float4*)(Ap + 4);
    *(float4*)&af[8]  = *(const float4*)(Ap + 8);
    *(float4*)&af[12] = *(const float4*)(Ap + 12);
#pragma unroll
    for (int j = 0; j < 16; ++j) bf[j] = Bp[(size_t)j * ldb];

    for (int k0 = 0; k0 < K; k0 += 32) {
        __syncthreads();
        {
            uint4 h0, l0, h1, l1;
            split_pack8(&af[0], h0, l0);
            split_pack8(&af[8], h1, l1);
            Ahi[aslot] = h0; Ahi[aslot + 16] = h1;
            Alo[aslot] = l0; Alo[aslot + 16] = l1;
            split_pack8(&bf[0], h0, l0);
            split_pack8(&bf[8], h1, l1);
            Bhi[bslot] = h0; Bhi[bslot + 16] = h1;
            Blo[bslot] = l0; Blo[bslot + 16] = l1;
        }
        __syncthreads();

        if (k0 + 32 < K) {
            const int kn = k0 + 32;
            *(float4*)&af[0]  = *(const float4*)(Ap + kn + 0);
            *(float4*)&af[4]  = *(const float4*)(Ap + kn + 4);
            *(float4*)&af[8]  = *(const float4*)(Ap + kn + 8);
            *(float4*)&af[12] = *(const float4*)(Ap + kn + 12);
#pragma unroll
            for (int j = 0; j < 16; ++j) bf[j] = Bp[(size_t)(kn + j) * ldb];
        }

        bhalf8 ah[4], al[4];
#pragma unroll
        for (int i = 0; i < 4; ++i) {
            const int s = ((wr * 4 + i) * 4 + kg) * 16 + lr;
            ah[i] = as_b8(Ahi[s]);
            al[i] = as_b8(Alo[s]);
        }
#pragma unroll
        for (int j = 0; j < 4; ++j) {
            const int s = ((wc * 4 + j) * 4 + kg) * 16 + lr;
            const bhalf8 bh = as_b8(Bhi[s]);
            const bhalf8 bl = as_b8(Blo[s]);
#pragma unroll
            for (int i = 0; i < 4; ++i) {
                acc[i][j] = __builtin_amdgcn_mfma_f32_16x16x32_bf16(ah[i], bl, acc[i][j], 0, 0, 0);
                acc[i][j] = __builtin_amdgcn_mfma_f32_16x16x32_bf16(al[i], bh, acc[i][j], 0, 0, 0);
                acc[i][j] = __builtin_amdgcn_mfma_f32_16x16x32_bf16(ah[i], bh, acc[i][j], 0, 0, 0);
            }
        }
    }

#pragma unroll
    for (int i = 0; i < 4; ++i) {
#pragma unroll
        for (int q = 0; q < 4; ++q) {
            const int m = m0 + (wr * 4 + i) * 16 + kg * 4 + q;
            int cm = m;
            if (crow) { cm = crow[m]; if (cm < 0) continue; }
            const float rs = rowscale ? rowscale[m] : 1.f;
#pragma unroll
            for (int j = 0; j < 4; ++j) {
                const int n = n0 + (wc * 4 + j) * 16 + lr;
                float v = acc[i][j][q];
                if (bias) v += bias[n];
                v *= rs;
                const size_t off = (size_t)cm * ldc + n;
                if (accumulate) v += C[off];
                if (add1) v += add1[off];
                if (add2) v += add2[off];
                C[off] = v;
            }
        }
    }
}

// ---------------------------------------------------------------- RoPE (in place)
__global__ __launch_bounds__(256)
void rope_k(float* __restrict__ p, int nheads)
{
    const int idx = blockIdx.x * 256 + threadIdx.x;
    const int total = TT * nheads * (DH / 2);
    if (idx >= total) return;
    const int i  = idx & 63;
    const int hh = (idx >> 6) % nheads;
    const int tt = idx / (64 * nheads);
    const int s  = tt & (SS - 1);      // position within sequence (S pow2)
    const float freq = expf(-(float)i * (9.210340371976184f / 64.f)); // 10000^{-i/64}
    const float ang = (float)s * freq;
    float sn, cs;
    sincosf(ang, &sn, &cs);
    float* base = p + ((size_t)tt * nheads + hh) * DH;
    const float x1 = base[i], x2 = base[i + 64];
    base[i]      = x1 * cs - x2 * sn;
    base[i + 64] = x2 * cs + x1 * sn;
}

// ---------------------------------------------------------------- MFMA flash attention (split-bf16, 3-pass)
// Grid (S/64, NQ, B); 256 threads = 4 waves; wave w owns Q rows q0+16w..+15.
// KT=32 key tiles, causal, GQA (kv = hq>>3).  All matmuls use the verified
// GEMM fragment conventions: A lane: row=l&15,k=(l>>4)*8+j; B lane: col=l&15;
// C/D: col=l&15, row=(l>>4)*4+reg.  Q is pre-scaled/split into registers.
// K staged straight into B-fragment chunks (d-contiguous loads).  V goes via
// f32 LDS scratch -> transposed split chunks.  P (unnormalized probs) via f32
// LDS scratch -> split A-chunks; PV is 3-pass so P/V precision ~f32.
__global__ __launch_bounds__(256)
void attn_k(const float* __restrict__ qb, const float* __restrict__ kb,
            const float* __restrict__ vb, float* __restrict__ ob)
{
    __shared__ uint4 ch_hi[512], ch_lo[512];     // K chunks, then V chunks (16KB)
    __shared__ uint4 ph_hi[256], ph_lo[256];     // P chunks (8KB)
    __shared__ float vscr[32 * 132];             // V f32 scratch (16.5KB)
    __shared__ float pscr[64 * 33];              // P f32 scratch (8.25KB)

    const int t   = threadIdx.x;
    const int q0  = blockIdx.x * 64;
    const int hq  = blockIdx.y;
    const int bz  = blockIdx.z;
    const int kvh = hq >> 3;                    // NQ/NKV = 8
    const float scl = 0.08838834764831845f;     // 1/sqrt(128)

    const int w  = t >> 6, l = t & 63;
    const int lr = l & 15, kg = l >> 4;

    // Q fragments in registers (scaled then split -> exact hi+lo of scaled q)
    uint4 qh[4], ql[4];
    {
        const float* qrow = qb + ((size_t)(bz * SS + q0 + w * 16 + lr) * NQ + hq) * DH;
#pragma unroll
        for (int ks = 0; ks < 4; ++ks) {
            float f[8];
            *(float4*)&f[0] = *(const float4*)(qrow + ks * 32 + kg * 8);
            *(float4*)&f[4] = *(const float4*)(qrow + ks * 32 + kg * 8 + 4);
#pragma unroll
            for (int i = 0; i < 8; ++i) f[i] *= scl;
            split_pack8(f, qh[ks], ql[ks]);
        }
    }

    float m[4]    = {-1e30f, -1e30f, -1e30f, -1e30f};
    float lsum[4] = {0.f, 0.f, 0.f, 0.f};
    floatx4 accO[8];
#pragma unroll
    for (int fc = 0; fc < 8; ++fc) accO[fc] = (floatx4){0.f, 0.f, 0.f, 0.f};

    const int nk = q0 + 64;
    for (int k0 = 0; k0 < nk; k0 += 32) {
        __syncthreads();                       // (A) prev PV done with chunks
        // ---- stage K fragment chunks (d-contiguous, split in reg)
#pragma unroll
        for (int rr = 0; rr < 2; ++rr) {
            const int r = t + rr * 256;        // 512 runs: 32 rows x 16 d-runs
            const int ktrow = r >> 4, ri = r & 15;
            const float* kro = kb + ((size_t)(bz * SS + k0 + ktrow) * NKV + kvh) * DH + ri * 8;
            float f[8];
            *(float4*)&f[0] = *(const float4*)(kro);
            *(float4*)&f[4] = *(const float4*)(kro + 4);
            uint4 h, lo;
            split_pack8(f, h, lo);
            const int slot = (((ri >> 2) * 2 + (ktrow >> 4)) * 4 + (ri & 3)) * 16 + (ktrow & 15);
            ch_hi[slot] = h; ch_lo[slot] = lo;
        }
        // ---- stage V rows into f32 scratch (coalesced)
#pragma unroll
        for (int ff = 0; ff < 4; ++ff) {
            const int fi = t + ff * 256;       // 1024 float4s: 32 rows x 32
            const int vrow = fi >> 5, c4 = fi & 31;
            const float4 v = *(const float4*)(vb + ((size_t)(bz * SS + k0 + vrow) * NKV + kvh) * DH + c4 * 4);
            *(float4*)&vscr[vrow * 132 + c4 * 4] = v;
        }
        __syncthreads();                       // (B) K chunks + V scratch ready

        // ---- S = Q.K^T  (3-pass split-bf16), S rows = wave's 16 q-rows
        floatx4 sa[2];
        sa[0] = (floatx4){0.f, 0.f, 0.f, 0.f};
        sa[1] = (floatx4){0.f, 0.f, 0.f, 0.f};
#pragma unroll
        for (int ks = 0; ks < 4; ++ks) {
#pragma unroll
            for (int j = 0; j < 2; ++j) {
                const int s = ((ks * 2 + j) * 4 + kg) * 16 + lr;
                const bhalf8 kh = as_b8(ch_hi[s]);
                const bhalf8 kl = as_b8(ch_lo[s]);
                const bhalf8 aqh = as_b8(qh[ks]);
                const bhalf8 aql = as_b8(ql[ks]);
                sa[j] = __builtin_amdgcn_mfma_f32_16x16x32_bf16(aqh, kl, sa[j], 0, 0, 0);
                sa[j] = __builtin_amdgcn_mfma_f32_16x16x32_bf16(aql, kh, sa[j], 0, 0, 0);
                sa[j] = __builtin_amdgcn_mfma_f32_16x16x32_bf16(aqh, kh, sa[j], 0, 0, 0);
            }
        }

        // ---- online softmax in registers (4 rows per lane, 16-lane groups)
        float alpha[4];
#pragma unroll
        for (int q = 0; q < 4; ++q) {
            const int rowg = q0 + w * 16 + kg * 4 + q;
            float s0 = sa[0][q], s1 = sa[1][q];
            if (k0 + lr > rowg)      s0 = -1e30f;
            if (k0 + 16 + lr > rowg) s1 = -1e30f;
            float mt = fmaxf(s0, s1);
#pragma unroll
            for (int o = 1; o < 16; o <<= 1) mt = fmaxf(mt, __shfl_xor(mt, o, 64));
            const float mnew = fmaxf(m[q], mt);
            alpha[q] = __expf(m[q] - mnew);
            const float p0 = __expf(s0 - mnew);
            const float p1 = __expf(s1 - mnew);
            float ls = p0 + p1;
#pragma unroll
            for (int o = 1; o < 16; o <<= 1) ls += __shfl_xor(ls, o, 64);
            m[q] = mnew;
            lsum[q] = alpha[q] * lsum[q] + ls;
            const int row_local = w * 16 + kg * 4 + q;
            pscr[row_local * 33 + lr]      = p0;
            pscr[row_local * 33 + 16 + lr] = p1;
#pragma unroll
            for (int fc = 0; fc < 8; ++fc) accO[fc][q] *= alpha[q];
        }
        __syncthreads();                       // (C) K reads + pscr writes done

        // ---- convert P -> A-chunks, V -> B-chunks (reusing K chunk region)
        {
            const int plr = t & 15, pkg = (t >> 4) & 3, prb = t >> 6;  // slot t
            float f[8];
#pragma unroll
            for (int i = 0; i < 8; ++i) f[i] = pscr[(prb * 16 + plr) * 33 + pkg * 8 + i];
            uint4 h, lo;
            split_pack8(f, h, lo);
            ph_hi[t] = h; ph_lo[t] = lo;
        }
#pragma unroll
        for (int rr = 0; rr < 2; ++rr) {
            const int s = t + rr * 256;        // 512 V chunk slots
            const int vlr = s & 15, vkg = (s >> 4) & 3, vfc = s >> 6;
            float g[8];
#pragma unroll
            for (int i = 0; i < 8; ++i) g[i] = vscr[(vkg * 8 + i) * 132 + vfc * 16 + vlr];
            uint4 vh, vl;
            split_pack8(g, vh, vl);
            ch_hi[s] = vh; ch_lo[s] = vl;
        }
        __syncthreads();                       // (D) P/V chunks ready

        // ---- O += P.V  (3-pass split-bf16)
        const bhalf8 pah = as_b8(ph_hi[(w * 4 + kg) * 16 + lr]);
        const bhalf8 pal = as_b8(ph_lo[(w * 4 + kg) * 16 + lr]);
#pragma unroll
        for (int fc = 0; fc < 8; ++fc) {
            const int s = (fc * 4 + kg) * 16 + lr;
            const bhalf8 vh = as_b8(ch_hi[s]);
            const bhalf8 vl = as_b8(ch_lo[s]);
            accO[fc] = __builtin_amdgcn_mfma_f32_16x16x32_bf16(pah, vl, accO[fc], 0, 0, 0);
            accO[fc] = __builtin_amdgcn_mfma_f32_16x16x32_bf16(pal, vh, accO[fc], 0, 0, 0);
            accO[fc] = __builtin_amdgcn_mfma_f32_16x16x32_bf16(pah, vh, accO[fc], 0, 0, 0);
        }
    }

    // ---- epilogue: normalize by row sum, scatter (C layout: col=lr, row=kg*4+q)
#pragma unroll
    for (int q = 0; q < 4; ++q) {
        const float inv = 1.f / lsum[q];
        float* orow = ob + ((size_t)(bz * SS + q0 + w * 16 + kg * 4 + q) * NQ + hq) * DH;
#pragma unroll
        for (int fc = 0; fc < 8; ++fc)
            orow[fc * 16 + lr] = accO[fc][q] * inv;
    }
}

// ---------------------------------------------------------------- router (+ shared sigmoid gate)
__global__ __launch_bounds__(256)
void router_k(const float* __restrict__ tb, const float* __restrict__ rw,
              const float* __restrict__ sgw, float* __restrict__ dw,
              float* __restrict__ gs)
{
    const int tok = blockIdx.x;
    const float* xr = tb + (size_t)tok * HH;
    float acc[EE] = {};
    float ag = 0.f;
    for (int h = threadIdx.x; h < HH; h += 256) {
        const float xv = xr[h];
        const float4 r0 = *(const float4*)(rw + (size_t)h * EE);
        const float4 r1 = *(const float4*)(rw + (size_t)h * EE + 4);
        acc[0] += xv * r0.x; acc[1] += xv * r0.y; acc[2] += xv * r0.z; acc[3] += xv * r0.w;
        acc[4] += xv * r1.x; acc[5] += xv * r1.y; acc[6] += xv * r1.z; acc[7] += xv * r1.w;
        ag += xv * sgw[h];
    }
#pragma unroll
    for (int e = 0; e < EE; ++e)
#pragma unroll
        for (int o = 32; o > 0; o >>= 1) acc[e] += __shfl_down(acc[e], o, 64);
#pragma unroll
    for (int o = 32; o > 0; o >>= 1) ag += __shfl_down(ag, o, 64);
    __shared__ float red[4][EE + 1];
    if ((threadIdx.x & 63) == 0) {
        const int w = threadIdx.x >> 6;
#pragma unroll
        for (int e = 0; e < EE; ++e) red[w][e] = acc[e];
        red[w][EE] = ag;
    }
    __syncthreads();
    if (threadIdx.x == 0) {
        float l[EE];
#pragma unroll
        for (int e = 0; e < EE; ++e) l[e] = red[0][e] + red[1][e] + red[2][e] + red[3][e];
        const float g = red[0][EE] + red[1][EE] + red[2][EE] + red[3][EE];
        gs[tok] = 1.f / (1.f + expf(-g));
        float m = l[0];
        for (int e = 1; e < EE; ++e) m = fmaxf(m, l[e]);
        float p[EE]; float sum = 0.f;
        for (int e = 0; e < EE; ++e) { p[e] = expf(l[e] - m); sum += p[e]; }
        for (int e = 0; e < EE; ++e) p[e] /= sum;
        bool used[EE] = {};
        float wsum = 0.f;
        for (int k = 0; k < KSEL; ++k) {       // top-4, ties -> lowest index (lax.top_k)
            int bi = 0; float bv = -1.f;
            for (int e = 0; e < EE; ++e)
                if (!used[e] && p[e] > bv) { bv = p[e]; bi = e; }
            used[bi] = true; wsum += bv;
        }
        for (int e = 0; e < EE; ++e)
            dw[(size_t)tok * EE + e] = used[e] ? p[e] / wsum : 0.f;
    }
}

// ---------------------------------------------------------------- sparse-MoE routing lists
__global__ void route_init_k(int* __restrict__ cnt)
{
    if (threadIdx.x < EE) cnt[threadIdx.x] = 0;
}

__global__ __launch_bounds__(256)
void route_fill_k(const float* __restrict__ dw, int* __restrict__ cnt,
                  int* __restrict__ tokidx, float* __restrict__ tokw)
{
    const int t = blockIdx.x * 256 + threadIdx.x;
    if (t >= TT) return;
#pragma unroll
    for (int e = 0; e < EE; ++e) {
        const float w = dw[(size_t)t * EE + e];
        if (w > 0.f) {
            const int pos = atomicAdd(cnt + e, 1);
            tokidx[e * TT + pos] = t;
            tokw[e * TT + pos]   = w;
        }
    }
}

// pad each expert's list to a multiple of 128 (GEMM M-tile) with -1 sentinels
__global__ void route_pad_k(const int* __restrict__ cnt, int* __restrict__ mpad,
                            int* __restrict__ tokidx)
{
    const int e = blockIdx.x;
    const int c = cnt[e];
    const int mp = (c + 127) & ~127;
    if (threadIdx.x == 0) mpad[e] = mp;
    for (int i = c + threadIdx.x; i < mp; i += 64) tokidx[e * TT + i] = -1;
}

// ---------------------------------------------------------------- silu(g)*u (*dw[token,e]), optional row limit
__global__ __launch_bounds__(256)
void silu_mul_k(float* __restrict__ g, const float* __restrict__ u,
                const float* __restrict__ dw, int ecol, int icols, int n,
                const int* __restrict__ mlim)
{
    const int idx = blockIdx.x * 256 + threadIdx.x;
    if (idx >= n) return;
    if (mlim && idx >= (*mlim) * icols) return;
    const float gv = g[idx];
    const float uv = u[idx];
    float v = gv / (1.f + __expf(-gv)) * uv;
    if (dw) v *= dw[(size_t)(idx / icols) * EE + ecol];
    g[idx] = v;
}

// ---------------------------------------------------------------- launcher
extern "C" void kernel_launch(void* const* d_in, const int* in_sizes, int n_in,
                              void* d_out, int out_size, void* d_ws, size_t ws_size,
                              hipStream_t stream)
{
    (void)in_sizes; (void)n_in; (void)out_size;
    const float* x   = (const float*)d_in[0];
    const float* ln1 = (const float*)d_in[1];
    const float* wq  = (const float*)d_in[2];
    const float* bq  = (const float*)d_in[3];
    const float* wk  = (const float*)d_in[4];
    const float* bk  = (const float*)d_in[5];
    const float* wv  = (const float*)d_in[6];
    const float* bv  = (const float*)d_in[7];
    const float* wo  = (const float*)d_in[8];
    const float* ln2 = (const float*)d_in[9];
    const float* rww = (const float*)d_in[10];
    const float* wg  = (const float*)d_in[11];
    const float* wu  = (const float*)d_in[12];
    const float* wd  = (const float*)d_in[13];
    const float* swg = (const float*)d_in[14];
    const float* swu = (const float*)d_in[15];
    const float* swd = (const float*)d_in[16];
    const float* sgw = (const float*)d_in[17];
    float* out = (float*)d_out;

    // f32 workspace region; attnb aliases hbuf, tb aliases qb
    float* ws   = (float*)d_ws;
    float* hbuf = ws;
    float* qb   = hbuf + (size_t)TT * HH;
    float* kb   = qb   + (size_t)TT * NQ * DH;
    float* vb   = kb   + (size_t)TT * NKV * DH;
    float* x1   = vb   + (size_t)TT * NKV * DH;
    float* moe  = x1   + (size_t)TT * HH;
    float* gbuf = moe  + (size_t)TT * HH;
    float* ubuf = gbuf + (size_t)TT * IMOE;
    float* dw   = ubuf + (size_t)TT * IMOE;
    float* gs   = dw   + (size_t)TT * EE;
    int*   tokidx = (int*)(gs + TT);                 // [EE][TT]
    float* tokw   = (float*)(tokidx + (size_t)EE * TT); // [EE][TT]
    int*   cnt    = (int*)(tokw + (size_t)EE * TT);  // [EE]
    int*   mpad   = cnt + EE;                        // [EE]
    const size_t need_f32 = (size_t)((char*)(mpad + EE) - (char*)ws);
    if (ws_size < need_f32) return;                  // workspace too small

    // bf16 hi/lo weight planes (transposed [N][K]); 16B-aligned
    char* pc0 = (char*)(mpad + EE);
    pc0 = (char*)(((uintptr_t)pc0 + 15) & ~(uintptr_t)15);
    unsigned short* p = (unsigned short*)pc0;
    unsigned short* wq_th = p; p += (size_t)HH * (NQ * DH);
    unsigned short* wq_tl = p; p += (size_t)HH * (NQ * DH);
    unsigned short* wk_th = p; p += (size_t)HH * (NKV * DH);
    unsigned short* wk_tl = p; p += (size_t)HH * (NKV * DH);
    unsigned short* wv_th = p; p += (size_t)HH * (NKV * DH);
    unsigned short* wv_tl = p; p += (size_t)HH * (NKV * DH);
    unsigned short* wo_th = p; p += (size_t)HH * HH;
    unsigned short* wo_tl = p; p += (size_t)HH * HH;
    unsigned short* wg_th = p; p += (size_t)EE * HH * IMOE;
    unsigned short* wg_tl = p; p += (size_t)EE * HH * IMOE;
    unsigned short* wu_th = p; p += (size_t)EE * HH * IMOE;
    unsigned short* wu_tl = p; p += (size_t)EE * HH * IMOE;
    unsigned short* wd_th = p; p += (size_t)EE * IMOE * HH;
    unsigned short* wd_tl = p; p += (size_t)EE * IMOE * HH;
    unsigned short* sg_th = p; p += (size_t)HH * ISH;
    unsigned short* sg_tl = p; p += (size_t)HH * ISH;
    unsigned short* su_th = p; p += (size_t)HH * ISH;
    unsigned short* su_tl = p; p += (size_t)HH * ISH;
    unsigned short* sd_th = p; p += (size_t)ISH * HH;
    unsigned short* sd_tl = p; p += (size_t)ISH * HH;
    const size_t need_planes = (size_t)((char*)p - (char*)ws);
    const bool planes = (ws_size >= need_planes);

    float* attnb = hbuf;   // hbuf dead after q/k/v projections
    float* tb    = qb;     // qb dead after attention

    // 0) weight conversion (independent of activations; front-loaded)
    if (planes) {
        splitw_k<<<dim3((NQ * DH) / 64, HH / 64), 256, 0, stream>>>(wq, HH, NQ * DH, wq_th, wq_tl);
        splitw_k<<<dim3((NKV * DH) / 64, HH / 64), 256, 0, stream>>>(wk, HH, NKV * DH, wk_th, wk_tl);
        splitw_k<<<dim3((NKV * DH) / 64, HH / 64), 256, 0, stream>>>(wv, HH, NKV * DH, wv_th, wv_tl);
        splitw_k<<<dim3(HH / 64, HH / 64), 256, 0, stream>>>(wo, NQ * DH, HH, wo_th, wo_tl);
        splitw_k<<<dim3(IMOE / 64, HH / 64, EE), 256, 0, stream>>>(wg, HH, IMOE, wg_th, wg_tl);
        splitw_k<<<dim3(IMOE / 64, HH / 64, EE), 256, 0, stream>>>(wu, HH, IMOE, wu_th, wu_tl);
        splitw_k<<<dim3(HH / 64, IMOE / 64, EE), 256, 0, stream>>>(wd, IMOE, HH, wd_th, wd_tl);
        splitw_k<<<dim3(ISH / 64, HH / 64), 256, 0, stream>>>(swg, HH, ISH, sg_th, sg_tl);
        splitw_k<<<dim3(ISH / 64, HH / 64), 256, 0, stream>>>(swu, HH, ISH, su_th, su_tl);
        splitw_k<<<dim3(HH / 64, ISH / 64), 256, 0, stream>>>(swd, ISH, HH, sd_th, sd_tl);
    }

    // 1) pre-norm
    rmsnorm_k<<<TT, 256, 0, stream>>>(x, ln1, hbuf);
    // 2) q/k/v projections (+bias)
    if (planes) {
        gemm_p_k<<<dim3((NQ * DH) / 128, TT / 128), 256, 0, stream>>>(hbuf, HH, wq_th, wq_tl, HH, qb, NQ * DH, HH, bq, nullptr, nullptr, nullptr, 0, nullptr, nullptr, nullptr);
        gemm_p_k<<<dim3((NKV * DH) / 128, TT / 128), 256, 0, stream>>>(hbuf, HH, wk_th, wk_tl, HH, kb, NKV * DH, HH, bk, nullptr, nullptr, nullptr, 0, nullptr, nullptr, nullptr);
        gemm_p_k<<<dim3((NKV * DH) / 128, TT / 128), 256, 0, stream>>>(hbuf, HH, wv_th, wv_tl, HH, vb, NKV * DH, HH, bv, nullptr, nullptr, nullptr, 0, nullptr, nullptr, nullptr);
    } else {
        gemm_f_k<<<dim3((NQ * DH) / 128, TT / 128), 256, 0, stream>>>(hbuf, HH, wq, NQ * DH, qb, NQ * DH, HH, bq, nullptr, nullptr, nullptr, 0, nullptr, nullptr, nullptr);
        gemm_f_k<<<dim3((NKV * DH) / 128, TT / 128), 256, 0, stream>>>(hbuf, HH, wk, NKV * DH, kb, NKV * DH, HH, bk, nullptr, nullptr, nullptr, 0, nullptr, nullptr, nullptr);
        gemm_f_k<<<dim3((NKV * DH) / 128, TT / 128), 256, 0, stream>>>(hbuf, HH, wv, NKV * DH, vb, NKV * DH, HH, bv, nullptr, nullptr, nullptr, 0, nullptr, nullptr, nullptr);
    }
    // 3) RoPE
    rope_k<<<(TT * NQ * 64 + 255) / 256, 256, 0, stream>>>(qb, NQ);
    rope_k<<<(TT * NKV * 64 + 255) / 256, 256, 0, stream>>>(kb, NKV);
    // 4) causal GQA attention (MFMA)
    attn_k<<<dim3(SS / 64, NQ, BB), 256, 0, stream>>>(qb, kb, vb, attnb);
    // 5) output projection + residual
    if (planes)
        gemm_p_k<<<dim3(HH / 128, TT / 128), 256, 0, stream>>>(attnb, NQ * DH, wo_th, wo_tl, NQ * DH, x1, HH, NQ * DH, nullptr, nullptr, x, nullptr, 0, nullptr, nullptr, nullptr);
    else
        gemm_f_k<<<dim3(HH / 128, TT / 128), 256, 0, stream>>>(attnb, NQ * DH, wo, HH, x1, HH, NQ * DH, nullptr, nullptr, x, nullptr, 0, nullptr, nullptr, nullptr);
    // 6) post-attn norm + router (+ shared sigmoid gate)
    rmsnorm_k<<<TT, 256, 0, stream>>>(x1, ln2, tb);
    router_k<<<TT, 256, 0, stream>>>(tb, rww, sgw, dw, gs);
    // 6b) sparse routing lists + zero the MoE accumulator
    zero_k<<<(TT * HH / 4 + 255) / 256, 256, 0, stream>>>(moe, TT * HH / 4);
    route_init_k<<<1, 64, 0, stream>>>(cnt);
    route_fill_k<<<(TT + 255) / 256, 256, 0, stream>>>(dw, cnt, tokidx, tokw);
    route_pad_k<<<EE, 64, 0, stream>>>(cnt, mpad, tokidx);
    // 7) experts — SPARSE: only tokens routed to expert e
    const int nmoe = TT * IMOE;
    for (int e = 0; e < EE; ++e) {
        const int*   idx = tokidx + e * TT;
        const float* twe = tokw + e * TT;
        const int*   ml  = mpad + e;
        if (planes) {
            gemm_p_k<<<dim3(IMOE / 128, TT / 128), 256, 0, stream>>>(tb, HH, wg_th + (size_t)e * HH * IMOE, wg_tl + (size_t)e * HH * IMOE, HH, gbuf, IMOE, HH, nullptr, nullptr, nullptr, nullptr, 0, idx, nullptr, ml);
            gemm_p_k<<<dim3(IMOE / 128, TT / 128), 256, 0, stream>>>(tb, HH, wu_th + (size_t)e * HH * IMOE, wu_tl + (size_t)e * HH * IMOE, HH, ubuf, IMOE, HH, nullptr, nullptr, nullptr, nullptr, 0, idx, nullptr, ml);
            silu_mul_k<<<(nmoe + 255) / 256, 256, 0, stream>>>(gbuf, ubuf, nullptr, 0, IMOE, nmoe, ml);
            gemm_p_k<<<dim3(HH / 128, TT / 128), 256, 0, stream>>>(gbuf, IMOE, wd_th + (size_t)e * IMOE * HH, wd_tl + (size_t)e * IMOE * HH, IMOE, moe, HH, IMOE, nullptr, twe, nullptr, nullptr, 1, nullptr, idx, ml);
        } else {
            const float* wge = wg + (size_t)e * HH * IMOE;
            const float* wue = wu + (size_t)e * HH * IMOE;
            const float* wde = wd + (size_t)e * IMOE * HH;
            gemm_f_k<<<dim3(IMOE / 128, TT / 128), 256, 0, stream>>>(tb, HH, wge, IMOE, gbuf, IMOE, HH, nullptr, nullptr, nullptr, nullptr, 0, idx, nullptr, ml);
            gemm_f_k<<<dim3(IMOE / 128, TT / 128), 256, 0, stream>>>(tb, HH, wue, IMOE, ubuf, IMOE, HH, nullptr, nullptr, nullptr, nullptr, 0, idx, nullptr, ml);
            silu_mul_k<<<(nmoe + 255) / 256, 256, 0, stream>>>(gbuf, ubuf, nullptr, 0, IMOE, nmoe, ml);
            gemm_f_k<<<dim3(HH / 128, TT / 128), 256, 0, stream>>>(gbuf, IMOE, wde, HH, moe, HH, IMOE, nullptr, twe, nullptr, nullptr, 1, nullptr, idx, ml);
        }
    }
    // 8) shared expert, chunked over I_SH in 4 x 1408; last chunk fuses final residual sum
    for (int c = 0; c < 4; ++c) {
        if (planes) {
            gemm_p_k<<<dim3(IMOE / 128, TT / 128), 256, 0, stream>>>(tb, HH, sg_th + (size_t)c * IMOE * HH, sg_tl + (size_t)c * IMOE * HH, HH, gbuf, IMOE, HH, nullptr, nullptr, nullptr, nullptr, 0, nullptr, nullptr, nullptr);
            gemm_p_k<<<dim3(IMOE / 128, TT / 128), 256, 0, stream>>>(tb, HH, su_th + (size_t)c * IMOE * HH, su_tl + (size_t)c * IMOE * HH, HH, ubuf, IMOE, HH, nullptr, nullptr, nullptr, nullptr, 0, nullptr, nullptr, nullptr);
            silu_mul_k<<<(nmoe + 255) / 256, 256, 0, stream>>>(gbuf, ubuf, nullptr, 0, IMOE, nmoe, nullptr);
            if (c < 3)
                gemm_p_k<<<dim3(HH / 128, TT / 128), 256, 0, stream>>>(gbuf, IMOE, sd_th + (size_t)c * IMOE, sd_tl + (size_t)c * IMOE, ISH, moe, HH, IMOE, nullptr, gs, nullptr, nullptr, 1, nullptr, nullptr, nullptr);
            else  // out = x1 + moe + gs .* (hs_c @ swdown_c)
                gemm_p_k<<<dim3(HH / 128, TT / 128), 256, 0, stream>>>(gbuf, IMOE, sd_th + (size_t)c * IMOE, sd_tl + (size_t)c * IMOE, ISH, out, HH, IMOE, nullptr, gs, moe, x1, 0, nullptr, nullptr, nullptr);
        } else {
            const float* swgc = swg + (size_t)c * IMOE;
            const float* swuc = swu + (size_t)c * IMOE;
            const float* swdc = swd + (size_t)c * IMOE * HH;
            gemm_f_k<<<dim3(IMOE / 128, TT / 128), 256, 0, stream>>>(tb, HH, swgc, ISH, gbuf, IMOE, HH, nullptr, nullptr, nullptr, nullptr, 0, nullptr, nullptr, nullptr);
            gemm_f_k<<<dim3(IMOE / 128, TT / 128), 256, 0, stream>>>(tb, HH, swuc, ISH, ubuf, IMOE, HH, nullptr, nullptr, nullptr, nullptr, 0, nullptr, nullptr, nullptr);
            silu_mul_k<<<(nmoe + 255) / 256, 256, 0, stream>>>(gbuf, ubuf, nullptr, 0, IMOE, nmoe, nullptr);
            if (c < 3)
                gemm_f_k<<<dim3(HH / 128, TT / 128), 256, 0, stream>>>(gbuf, IMOE, swdc, HH, moe, HH, IMOE, nullptr, gs, nullptr, nullptr, 1, nullptr, nullptr, nullptr);
            else
                gemm_f_k<<<dim3(HH / 128, TT / 128), 256, 0, stream>>>(gbuf, IMOE, swdc, HH, out, HH, IMOE, nullptr, gs, moe, x1, 0, nullptr, nullptr, nullptr);
        }
    }
}